// Round 7
// baseline (948.259 us; speedup 1.0000x reference)
//
#include <hip/hip_runtime.h>
#include <hip/hip_bf16.h>

// SetTransformer encoder forward. B=32,N=2048,D=256,H=8,dh=32,NI=64,NL=3,NS=32.
// Round 7: z-merged GEMM — one block computes ALL weights (K,V,Q / K,V) for its
// A-row panel, so A is fetched from HBM exactly once (z>=1 hits the block's own
// XCD L2). Epilogue staging uses +16B row padding instead of XOR swizzle.

typedef __attribute__((ext_vector_type(8))) short short8;
typedef __attribute__((ext_vector_type(4))) float f32x4;
typedef __attribute__((ext_vector_type(4))) ushort ushort4v;

__device__ __forceinline__ ushort f2bf(float f) {
  uint u = __builtin_bit_cast(uint, f);
  u += 0x7fffu + ((u >> 16) & 1u);
  return (ushort)(u >> 16);
}
__device__ __forceinline__ float bf2f(ushort h) {
  uint u = (uint)h << 16;
  return __builtin_bit_cast(float, u);
}

// ---------------- weight prep: transpose 256x256 f32 [k][n] -> bf16 [n][k] ----------------
__global__ __launch_bounds__(256) void prep_weights(
    const float* __restrict__ Wq, const float* __restrict__ Wk,
    const float* __restrict__ Wv, const float* __restrict__ Wo,
    const float* __restrict__ pWq, const float* __restrict__ pWk,
    const float* __restrict__ pWv, const float* __restrict__ pWo,
    ushort* __restrict__ wt)
{
  __shared__ float tile[64][65];
  const int m = blockIdx.y;          // 0..27
  const int t = blockIdx.x;          // 0..15
  const int tr = (t >> 2) * 64;      // k block
  const int tc = (t & 3) * 64;       // n block
  const float* src;
  if (m < 24) {
    int l = m >> 3, s = (m >> 2) & 1, w = m & 3;
    const float* base = (w == 0) ? Wq : (w == 1) ? Wk : (w == 2) ? Wv : Wo;
    src = base + (size_t)(l * 2 + s) * 65536;
  } else {
    int w = m & 3;
    src = (w == 0) ? pWq : (w == 1) ? pWk : (w == 2) ? pWv : pWo;
  }
  const int tid = threadIdx.x;
  const int cn = tid & 63;
  const int rk = tid >> 6;
#pragma unroll
  for (int j = 0; j < 16; ++j) {
    int kl = rk + j * 4;
    tile[kl][cn] = src[(size_t)(tr + kl) * 256 + tc + cn];
  }
  __syncthreads();
  ushort* dst = wt + (size_t)m * 65536;
#pragma unroll
  for (int j = 0; j < 16; ++j) {
    int nl = rk + j * 4;
    dst[(size_t)(tc + nl) * 256 + tr + cn] = f2bf(tile[cn][nl]);
  }
}

// ---------------- input projection + exact gelu -> bf16, 8 rows/block ----------------
__global__ __launch_bounds__(256) void proj_gelu(
    const float* __restrict__ xv, const float* __restrict__ yt,
    const float* __restrict__ pW, const float* __restrict__ pb,
    ushort* __restrict__ xb)
{
  const int d = threadIdx.x;
  const int row0 = blockIdx.x * 8;
  const float w0 = pW[d], w1 = pW[256 + d], w2 = pW[512 + d], w3 = pW[768 + d];
  const float bz = pb[d];
#pragma unroll
  for (int rr = 0; rr < 8; ++rr) {
    int row = row0 + rr;
    float f0 = xv[(size_t)row * 3 + 0];
    float f1 = xv[(size_t)row * 3 + 1];
    float f2 = xv[(size_t)row * 3 + 2];
    float f3 = yt[row];
    float a = bz + f0 * w0 + f1 * w1 + f2 * w2 + f3 * w3;
    float g = 0.5f * a * (1.f + erff(a * 0.70710678118654752f));
    xb[(size_t)row * 256 + d] = f2bf(g);
  }
}

// ---------------- batched tiny q-projections (f32 A, M=64/32) ----------------
__global__ __launch_bounds__(256) void gemm_q(
    const float* __restrict__ iI, const float* __restrict__ pS,
    const ushort* __restrict__ wt, const float* __restrict__ ibq,
    const float* __restrict__ pbq, ushort* __restrict__ q_all)
{
  const int bq = blockIdx.x;
  const float* A; const ushort* Wt; const float* bias; ushort* out; int M;
  if (bq < 3) { A = iI + bq * 16384; Wt = wt + (size_t)(bq * 8) * 65536; bias = ibq + bq * 512; out = q_all + bq * 16384; M = 64; }
  else        { A = pS; Wt = wt + (size_t)24 * 65536; bias = pbq; out = q_all + 49152; M = 32; }
  const int tid = threadIdx.x;
  const int wave = tid >> 6, lane = tid & 63;
  const int l15 = lane & 15, l4 = lane >> 4, koff = l4 * 8;
  f32x4 acc[4][4];
#pragma unroll
  for (int i = 0; i < 4; ++i)
#pragma unroll
    for (int j = 0; j < 4; ++j) acc[i][j] = (f32x4)0.f;
#pragma unroll
  for (int ks = 0; ks < 8; ++ks) {
    short8 af[4];
#pragma unroll
    for (int mf = 0; mf < 4; ++mf) {
      if (mf * 16 < M) {
        const float* ap = A + (size_t)(mf * 16 + l15) * 256 + ks * 32 + koff;
        float4 f0 = *(const float4*)ap;
        float4 f1 = *(const float4*)(ap + 4);
        short8 sv;
        sv[0] = (short)f2bf(f0.x); sv[1] = (short)f2bf(f0.y);
        sv[2] = (short)f2bf(f0.z); sv[3] = (short)f2bf(f0.w);
        sv[4] = (short)f2bf(f1.x); sv[5] = (short)f2bf(f1.y);
        sv[6] = (short)f2bf(f1.z); sv[7] = (short)f2bf(f1.w);
        af[mf] = sv;
      } else af[mf] = (short8)0;
    }
#pragma unroll
    for (int nf = 0; nf < 4; ++nf) {
      short8 bf = *(const short8*)(Wt + (size_t)(wave * 64 + nf * 16 + l15) * 256 + ks * 32 + koff);
#pragma unroll
      for (int mf = 0; mf < 4; ++mf)
        acc[mf][nf] = __builtin_amdgcn_mfma_f32_16x16x32_bf16(af[mf], bf, acc[mf][nf], 0, 0, 0);
    }
  }
#pragma unroll
  for (int mf = 0; mf < 4; ++mf) {
    if (mf * 16 >= M) continue;
#pragma unroll
    for (int nf = 0; nf < 4; ++nf) {
      int col = wave * 64 + nf * 16 + l15;
      float bcol = bias[col];
#pragma unroll
      for (int r = 0; r < 4; ++r)
        out[(size_t)(mf * 16 + l4 * 4 + r) * 256 + col] = f2bf(acc[mf][nf][r] + bcol);
    }
  }
}

// ---------------- z-merged B-panel GEMM: out_z = epi(A @ W_z + bias_z), z=0..NZ-1 ----
// A bf16 [M][256], Wt_z bf16 [n][k]. grid = M/128 blocks, 512 threads (8 waves, 2x4).
// Per block: A panel fetched once from HBM; z-loop stages each W_z panel into LDS
// (2-bit XOR swizzle) and re-reads A from the local XCD L2. MFMA operands swapped
// (lane = 1 row x 4 consecutive cols). Epilogue: tile staged into padded LDS
// (ROWB=528, ~2-way banks) then stored as full 64B lines.
// EPI 0: +bias -> bf16.  EPI 3 (NZ=1): zr = A + relu(acc+bias); fused LayerNorm(zr).
template <int EPI, bool OUTF32, int NZ>
__global__ __launch_bounds__(512, 4) void gemm_bp(
    const ushort* __restrict__ A,
    const ushort* __restrict__ Wt0, const ushort* __restrict__ Wt1, const ushort* __restrict__ Wt2,
    const float* __restrict__ b0, const float* __restrict__ b1, const float* __restrict__ b2,
    void* __restrict__ o0, void* __restrict__ o1, void* __restrict__ o2,
    const float* __restrict__ lng, const float* __restrict__ lnb)
{
  constexpr int PS = 256 * 64;             // bytes per ks-plane (256 n-rows x 32 k x 2B)
  constexpr int ROWB = 512 + 16;           // padded staging row bytes
  __shared__ __align__(16) char Bs[128 * ROWB];  // 67.6KB: B panel (64KB) / out staging
  __shared__ float redbuf[(EPI == 3) ? 1280 : 4];

  const int tid = threadIdx.x;
  const int wave = tid >> 6, lane = tid & 63;
  const int wc = wave & 3, wr = wave >> 2;  // 2 row groups x 4 col groups
  const int l15 = lane & 15, l4 = lane >> 4;
  const int row0 = blockIdx.x * 128;
  const int sn = tid >> 1, sseg = tid & 1;  // staging coords: n row, 64-k segment

#pragma unroll
  for (int z = 0; z < NZ; ++z) {
    const ushort* Wt = (z == 0) ? Wt0 : ((z == 1) ? Wt1 : Wt2);
    const float* bias = (z == 0) ? b0 : ((z == 1) ? b1 : b2);
    void* outp = (z == 0) ? o0 : ((z == 1) ? o1 : o2);

    f32x4 acc[4][4];  // [mfa][nfb]; lane = (row l15, cols l4*4+i)
#pragma unroll
    for (int i = 0; i < 4; ++i)
#pragma unroll
      for (int j = 0; j < 4; ++j) acc[i][j] = (f32x4)0.f;

#pragma unroll
    for (int half = 0; half < 2; ++half) {
      if (z || half) __syncthreads();  // prior readers of Bs done
      {  // stage B half: 256 n-rows x 128 k; chunk' = chunk ^ ((sn>>1)&3)
        const ushort* src = Wt + (size_t)sn * 256 + half * 128 + sseg * 64;
#pragma unroll
        for (int c = 0; c < 8; ++c) {
          uint4 w = *(const uint4*)(src + c * 8);
          int plane = sseg * 2 + (c >> 2);
          char* dst = Bs + plane * PS + sn * 64 + (((c & 3) * 16) ^ (((sn >> 1) & 3) << 4));
          *(uint4*)dst = w;
        }
      }
      __syncthreads();
#pragma unroll
      for (int ks = 0; ks < 4; ++ks) {
        short8 af[4];
#pragma unroll
        for (int mfa = 0; mfa < 4; ++mfa)
          af[mfa] = *(const short8*)(A + (size_t)(row0 + wr * 64 + mfa * 16 + l15) * 256 + half * 128 + ks * 32 + l4 * 8);
#pragma unroll
        for (int nfb = 0; nfb < 4; ++nfb) {
          int n = wc * 64 + nfb * 16 + l15;
          short8 bf = *(const short8*)(Bs + ks * PS + n * 64 + ((l4 * 16) ^ (((n >> 1) & 3) << 4)));
#pragma unroll
          for (int mfa = 0; mfa < 4; ++mfa)  // swapped: D row<-l15(A-row), cols<-l4*4+i(n)
            acc[mfa][nfb] = __builtin_amdgcn_mfma_f32_16x16x32_bf16(bf, af[mfa], acc[mfa][nfb], 0, 0, 0);
        }
      }
    }

    if constexpr (EPI == 0) {
      __syncthreads();  // all waves done reading Bs
#pragma unroll
      for (int nfb = 0; nfb < 4; ++nfb) {
        int col0 = wc * 64 + nfb * 16 + l4 * 4;
        f32x4 bv = *(const f32x4*)(bias + col0);
#pragma unroll
        for (int mfa = 0; mfa < 4; ++mfa) {
          int row = wr * 64 + mfa * 16 + l15;
          ushort4v pk;
#pragma unroll
          for (int i = 0; i < 4; ++i) pk[i] = f2bf(acc[mfa][nfb][i] + bv[i]);
          *(ushort4v*)(Bs + row * ROWB + col0 * 2) = pk;
        }
      }
      __syncthreads();
      const int srow = tid >> 2, seg = tid & 3;
      ushort* gdst = (ushort*)outp + (size_t)(row0 + srow) * 256;
#pragma unroll
      for (int it = 0; it < 8; ++it) {
        int colb = seg * 16 + it * 64;
        uint4 v = *(const uint4*)(Bs + srow * ROWB + colb);
        *(uint4*)(gdst + colb / 2) = v;
      }
    } else {
      // EPI3 (NZ==1): zr = resid + relu(acc+bias); block LayerNorm over 256-wide rows
      float* red1 = redbuf;          // [4][128]
      float* red2 = redbuf + 512;    // [4][128]
      float* mv_ = redbuf + 1024;    // [128]
      float* rv_ = redbuf + 1152;    // [128]
      float s1[4] = {0.f, 0.f, 0.f, 0.f}, s2[4] = {0.f, 0.f, 0.f, 0.f};
#pragma unroll
      for (int nfb = 0; nfb < 4; ++nfb) {
        int col0 = wc * 64 + nfb * 16 + l4 * 4;
        f32x4 bv = *(const f32x4*)(bias + col0);
#pragma unroll
        for (int mfa = 0; mfa < 4; ++mfa) {
          size_t row = (size_t)row0 + wr * 64 + mfa * 16 + l15;
          ushort4v rz = *(const ushort4v*)(A + row * 256 + col0);
#pragma unroll
          for (int i = 0; i < 4; ++i) {
            float zz = bf2f(rz[i]) + fmaxf(acc[mfa][nfb][i] + bv[i], 0.f);
            acc[mfa][nfb][i] = zz;
            s1[mfa] += zz;
            s2[mfa] += zz * zz;
          }
        }
      }
#pragma unroll
      for (int mfa = 0; mfa < 4; ++mfa) {
        s1[mfa] += __shfl_xor(s1[mfa], 16); s1[mfa] += __shfl_xor(s1[mfa], 32);
        s2[mfa] += __shfl_xor(s2[mfa], 16); s2[mfa] += __shfl_xor(s2[mfa], 32);
      }
      if (l4 == 0) {
#pragma unroll
        for (int mfa = 0; mfa < 4; ++mfa) {
          red1[wc * 128 + wr * 64 + mfa * 16 + l15] = s1[mfa];
          red2[wc * 128 + wr * 64 + mfa * 16 + l15] = s2[mfa];
        }
      }
      __syncthreads();  // also drains Bs reads
      if (tid < 128) {
        float m1 = red1[tid] + red1[128 + tid] + red1[256 + tid] + red1[384 + tid];
        float m2 = red2[tid] + red2[128 + tid] + red2[256 + tid] + red2[384 + tid];
        float mean = m1 * 0.00390625f;
        float var = m2 * 0.00390625f - mean * mean;
        mv_[tid] = mean;
        rv_[tid] = rsqrtf(var + 1e-5f);
      }
      __syncthreads();
#pragma unroll
      for (int nfb = 0; nfb < 4; ++nfb) {
        int col0 = wc * 64 + nfb * 16 + l4 * 4;
        f32x4 gg = *(const f32x4*)(lng + col0);
        f32x4 bb = *(const f32x4*)(lnb + col0);
#pragma unroll
        for (int mfa = 0; mfa < 4; ++mfa) {
          int lr = wr * 64 + mfa * 16 + l15;
          float mean = mv_[lr], rs = rv_[lr];
          if constexpr (OUTF32) {
            f32x4 w;
#pragma unroll
            for (int i = 0; i < 4; ++i) w[i] = (acc[mfa][nfb][i] - mean) * rs * gg[i] + bb[i];
            *(f32x4*)((float*)outp + ((size_t)row0 + lr) * 256 + col0) = w;
          } else {
            ushort4v pk;
#pragma unroll
            for (int i = 0; i < 4; ++i) pk[i] = f2bf((acc[mfa][nfb][i] - mean) * rs * gg[i] + bb[i]);
            *(ushort4v*)(Bs + lr * ROWB + col0 * 2) = pk;
          }
        }
      }
      if constexpr (!OUTF32) {
        __syncthreads();
        const int srow = tid >> 2, seg = tid & 3;
        ushort* gdst = (ushort*)outp + (size_t)(row0 + srow) * 256;
#pragma unroll
        for (int it = 0; it < 8; ++it) {
          int colb = seg * 16 + it * 64;
          uint4 v = *(const uint4*)(Bs + srow * ROWB + colb);
          *(uint4*)(gdst + colb / 2) = v;
        }
      }
    }
  }
}

// ---------------- attn_big: nq small (64/32), nk=2048, masked, q shared across batch ----
template <int MF>
__global__ __launch_bounds__(512) void attn_big(
    const ushort* __restrict__ qb, const ushort* __restrict__ kb,
    const ushort* __restrict__ vb, const float* __restrict__ mask,
    ushort* __restrict__ O)
{
  __shared__ __align__(16) ushort Ps[8][64][72];
  __shared__ __align__(16) ushort Vt[8][32][72];
  const int h = blockIdx.x, b = blockIdx.y;
  const int tid = threadIdx.x;
  const int w = tid >> 6, lane = tid & 63;
  const int l15 = lane & 15, l4 = lane >> 4;
  const int koff = l4 * 8;
  const int kvbase = b * 2048;

  short8 qf[MF];
#pragma unroll
  for (int mf = 0; mf < MF; ++mf)
    qf[mf] = *(const short8*)(qb + (size_t)(mf * 16 + l15) * 256 + h * 32 + koff);

  f32x4 Oa[MF][2];
  float Mr[MF][4], Lr[MF][4];
#pragma unroll
  for (int mf = 0; mf < MF; ++mf) {
    Oa[mf][0] = (f32x4)0.f; Oa[mf][1] = (f32x4)0.f;
#pragma unroll
    for (int r = 0; r < 4; ++r) { Mr[mf][r] = -1e30f; Lr[mf][r] = 0.f; }
  }

  for (int c = 0; c < 4; ++c) {
    const int kc = w * 256 + c * 64;
    f32x4 S[MF][4];
#pragma unroll
    for (int nf = 0; nf < 4; ++nf) {
      short8 kf = *(const short8*)(kb + (size_t)(kvbase + kc + nf * 16 + l15) * 256 + h * 32 + koff);
#pragma unroll
      for (int mf = 0; mf < MF; ++mf)
        S[mf][nf] = __builtin_amdgcn_mfma_f32_16x16x32_bf16(qf[mf], kf, (f32x4)0.f, 0, 0, 0);
    }
    float mv[4];
#pragma unroll
    for (int nf = 0; nf < 4; ++nf)
      mv[nf] = mask[(size_t)b * 2048 + kc + nf * 16 + l15];
#pragma unroll
    for (int mf = 0; mf < MF; ++mf)
#pragma unroll
      for (int nf = 0; nf < 4; ++nf)
#pragma unroll
        for (int r = 0; r < 4; ++r) {
          float s = S[mf][nf][r] * 0.0625f;
          S[mf][nf][r] = (mv[nf] != 0.f) ? s : -1e4f;
        }
#pragma unroll
    for (int mf = 0; mf < MF; ++mf)
#pragma unroll
      for (int r = 0; r < 4; ++r) {
        float pm = fmaxf(fmaxf(S[mf][0][r], S[mf][1][r]), fmaxf(S[mf][2][r], S[mf][3][r]));
        pm = fmaxf(pm, __shfl_xor(pm, 1));
        pm = fmaxf(pm, __shfl_xor(pm, 2));
        pm = fmaxf(pm, __shfl_xor(pm, 4));
        pm = fmaxf(pm, __shfl_xor(pm, 8));
        float Mnew = fmaxf(Mr[mf][r], pm);
        float corr = __expf(Mr[mf][r] - Mnew);
        Mr[mf][r] = Mnew;
        float rs = 0.f;
#pragma unroll
        for (int nf = 0; nf < 4; ++nf) {
          float p = __expf(S[mf][nf][r] - Mnew);
          S[mf][nf][r] = p;
          rs += p;
        }
        rs += __shfl_xor(rs, 1);
        rs += __shfl_xor(rs, 2);
        rs += __shfl_xor(rs, 4);
        rs += __shfl_xor(rs, 8);
        Lr[mf][r] = Lr[mf][r] * corr + rs;
        Oa[mf][0][r] *= corr;
        Oa[mf][1][r] *= corr;
      }
#pragma unroll
    for (int dblk = 0; dblk < 4; ++dblk) {
      short8 vv = *(const short8*)(vb + (size_t)(kvbase + kc + lane) * 256 + h * 32 + dblk * 8);
#pragma unroll
      for (int j = 0; j < 8; ++j) Vt[w][dblk * 8 + j][lane] = (ushort)vv[j];
    }
#pragma unroll
    for (int mf = 0; mf < MF; ++mf)
#pragma unroll
      for (int nf = 0; nf < 4; ++nf)
#pragma unroll
        for (int r = 0; r < 4; ++r)
          Ps[w][mf * 16 + l4 * 4 + r][nf * 16 + l15] = f2bf(S[mf][nf][r]);
#pragma unroll
    for (int ks = 0; ks < 2; ++ks) {
      short8 pf[MF];
#pragma unroll
      for (int mf = 0; mf < MF; ++mf)
        pf[mf] = *(const short8*)&Ps[w][mf * 16 + l15][ks * 32 + koff];
#pragma unroll
      for (int nf2 = 0; nf2 < 2; ++nf2) {
        short8 vf = *(const short8*)&Vt[w][nf2 * 16 + l15][ks * 32 + koff];
#pragma unroll
        for (int mf = 0; mf < MF; ++mf)
          Oa[mf][nf2] = __builtin_amdgcn_mfma_f32_16x16x32_bf16(pf[mf], vf, Oa[mf][nf2], 0, 0, 0);
      }
    }
  }

  __syncthreads();
  float* Mw = (float*)&Ps[0][0][0];
  float* Lw = Mw + 512;
  float* Ow = Lw + 512;  // [8][64][33]
#pragma unroll
  for (int mf = 0; mf < MF; ++mf)
#pragma unroll
    for (int r = 0; r < 4; ++r) {
      int row = mf * 16 + l4 * 4 + r;
      if (l15 == 0) { Mw[w * 64 + row] = Mr[mf][r]; Lw[w * 64 + row] = Lr[mf][r]; }
#pragma unroll
      for (int nf2 = 0; nf2 < 2; ++nf2)
        Ow[(w * 64 + row) * 33 + nf2 * 16 + l15] = Oa[mf][nf2][r];
    }
  __syncthreads();
  const int NQ = MF * 16;
  int row = tid >> 3, dg = tid & 7;
  if (row < NQ) {
    float mm = -1e30f;
#pragma unroll
    for (int s = 0; s < 8; ++s) mm = fmaxf(mm, Mw[s * 64 + row]);
    float den = 0.f, es[8];
#pragma unroll
    for (int s = 0; s < 8; ++s) {
      es[s] = __expf(Mw[s * 64 + row] - mm);
      den += Lw[s * 64 + row] * es[s];
    }
    float invden = 1.f / den;
    ushort4v pk;
#pragma unroll
    for (int i = 0; i < 4; ++i) {
      int d = dg * 4 + i;
      float num = 0.f;
#pragma unroll
      for (int s = 0; s < 8; ++s) num += Ow[(s * 64 + row) * 33 + d] * es[s];
      float qv = bf2f(qb[(size_t)row * 256 + h * 32 + d]);
      pk[i] = f2bf(qv + num * invden);
    }
    *(ushort4v*)(O + (size_t)(b * NQ + row) * 256 + h * 32 + dg * 4) = pk;
  }
}

// ---------------- attn_small: nq=2048, nk=64, unmasked, fused LayerNorm ----------------
__global__ __launch_bounds__(512) void attn_small(
    const ushort* __restrict__ qb, const ushort* __restrict__ kb,
    const ushort* __restrict__ vb, const float* __restrict__ lng,
    const float* __restrict__ lnb, ushort* __restrict__ O)
{
  __shared__ __align__(16) ushort Ps[8][64][72];
  __shared__ __align__(16) ushort Vt[8][32][72];
  __shared__ float red1[8][64], red2[8][64], mv_[64], rv_[64];
  const int qt = blockIdx.x, b = blockIdx.y;
  const int tid = threadIdx.x;
  const int w = tid >> 6, lane = tid & 63;  // w = head
  const int l15 = lane & 15, l4 = lane >> 4;
  const int koff = l4 * 8;
  const size_t qrow0 = (size_t)b * 2048 + qt * 64;
  const int kvbase = b * 64;
  const int h = w;

  short8 qf[4];
#pragma unroll
  for (int mf = 0; mf < 4; ++mf)
    qf[mf] = *(const short8*)(qb + (qrow0 + mf * 16 + l15) * 256 + h * 32 + koff);

  f32x4 S[4][4];
#pragma unroll
  for (int nf = 0; nf < 4; ++nf) {
    short8 kf = *(const short8*)(kb + (size_t)(kvbase + nf * 16 + l15) * 256 + h * 32 + koff);
#pragma unroll
    for (int mf = 0; mf < 4; ++mf)
      S[mf][nf] = __builtin_amdgcn_mfma_f32_16x16x32_bf16(qf[mf], kf, (f32x4)0.f, 0, 0, 0);
  }
  float Lr[4][4];
#pragma unroll
  for (int mf = 0; mf < 4; ++mf)
#pragma unroll
    for (int r = 0; r < 4; ++r) {
      float pm = fmaxf(fmaxf(S[mf][0][r], S[mf][1][r]), fmaxf(S[mf][2][r], S[mf][3][r])) * 0.0625f;
      pm = fmaxf(pm, __shfl_xor(pm, 1));
      pm = fmaxf(pm, __shfl_xor(pm, 2));
      pm = fmaxf(pm, __shfl_xor(pm, 4));
      pm = fmaxf(pm, __shfl_xor(pm, 8));
      float rs = 0.f;
#pragma unroll
      for (int nf = 0; nf < 4; ++nf) {
        float p = __expf(S[mf][nf][r] * 0.0625f - pm);
        S[mf][nf][r] = p;
        rs += p;
      }
      rs += __shfl_xor(rs, 1);
      rs += __shfl_xor(rs, 2);
      rs += __shfl_xor(rs, 4);
      rs += __shfl_xor(rs, 8);
      Lr[mf][r] = rs;
    }
#pragma unroll
  for (int dblk = 0; dblk < 4; ++dblk) {
    short8 vv = *(const short8*)(vb + (size_t)(kvbase + lane) * 256 + h * 32 + dblk * 8);
#pragma unroll
    for (int j = 0; j < 8; ++j) Vt[w][dblk * 8 + j][lane] = (ushort)vv[j];
  }
#pragma unroll
  for (int mf = 0; mf < 4; ++mf)
#pragma unroll
    for (int nf = 0; nf < 4; ++nf)
#pragma unroll
      for (int r = 0; r < 4; ++r)
        Ps[w][mf * 16 + l4 * 4 + r][nf * 16 + l15] = f2bf(S[mf][nf][r]);
  f32x4 Oa[4][2];
#pragma unroll
  for (int mf = 0; mf < 4; ++mf) { Oa[mf][0] = (f32x4)0.f; Oa[mf][1] = (f32x4)0.f; }
#pragma unroll
  for (int ks = 0; ks < 2; ++ks) {
    short8 pf[4];
#pragma unroll
    for (int mf = 0; mf < 4; ++mf)
      pf[mf] = *(const short8*)&Ps[w][mf * 16 + l15][ks * 32 + koff];
#pragma unroll
    for (int nf2 = 0; nf2 < 2; ++nf2) {
      short8 vf = *(const short8*)&Vt[w][nf2 * 16 + l15][ks * 32 + koff];
#pragma unroll
      for (int mf = 0; mf < 4; ++mf)
        Oa[mf][nf2] = __builtin_amdgcn_mfma_f32_16x16x32_bf16(pf[mf], vf, Oa[mf][nf2], 0, 0, 0);
    }
  }
  float s1[4][4], s2[4][4];
#pragma unroll
  for (int mf = 0; mf < 4; ++mf)
#pragma unroll
    for (int r = 0; r < 4; ++r) {
      float invL = 1.f / Lr[mf][r];
      s1[mf][r] = 0.f; s2[mf][r] = 0.f;
#pragma unroll
      for (int nf2 = 0; nf2 < 2; ++nf2) {
        int col = h * 32 + nf2 * 16 + l15;
        size_t row = qrow0 + mf * 16 + l4 * 4 + r;
        float z = bf2f(qb[row * 256 + col]) + Oa[mf][nf2][r] * invL;
        Oa[mf][nf2][r] = z;
        s1[mf][r] += z;
        s2[mf][r] += z * z;
      }
#pragma unroll
      for (int off = 1; off < 16; off <<= 1) {
        s1[mf][r] += __shfl_xor(s1[mf][r], off);
        s2[mf][r] += __shfl_xor(s2[mf][r], off);
      }
      if (l15 == 0) {
        int row = mf * 16 + l4 * 4 + r;
        red1[w][row] = s1[mf][r];
        red2[w][row] = s2[mf][r];
      }
    }
  __syncthreads();
  if (tid < 64) {
    float m1 = 0.f, m2 = 0.f;
#pragma unroll
    for (int s = 0; s < 8; ++s) { m1 += red1[s][tid]; m2 += red2[s][tid]; }
    float mean = m1 * 0.00390625f;
    float var = m2 * 0.00390625f - mean * mean;
    mv_[tid] = mean;
    rv_[tid] = rsqrtf(var + 1e-5f);
  }
  __syncthreads();
#pragma unroll
  for (int nf2 = 0; nf2 < 2; ++nf2) {
    int col = h * 32 + nf2 * 16 + l15;
    float gc = lng[col], bc = lnb[col];
#pragma unroll
    for (int mf = 0; mf < 4; ++mf)
#pragma unroll
      for (int r = 0; r < 4; ++r) {
        int row = mf * 16 + l4 * 4 + r;
        float v = (Oa[mf][nf2][r] - mv_[row]) * rv_[row] * gc + bc;
        O[(qrow0 + row) * 256 + col] = f2bf(v);
      }
  }
}

// ---------------- small LayerNorm: bf16 in/out, wave per row ----------------
__global__ __launch_bounds__(256) void ln4(
    const ushort* __restrict__ in, ushort* __restrict__ out,
    const float* __restrict__ g, const float* __restrict__ bb)
{
  const int w = threadIdx.x >> 6, lane = threadIdx.x & 63;
  const size_t row = (size_t)blockIdx.x * 4 + w;
  ushort4v u = *(const ushort4v*)(in + row * 256 + lane * 4);
  float v[4];
#pragma unroll
  for (int i = 0; i < 4; ++i) v[i] = bf2f(u[i]);
  float s1 = v[0] + v[1] + v[2] + v[3];
  float s2 = v[0] * v[0] + v[1] * v[1] + v[2] * v[2] + v[3] * v[3];
#pragma unroll
  for (int off = 1; off < 64; off <<= 1) {
    s1 += __shfl_xor(s1, off);
    s2 += __shfl_xor(s2, off);
  }
  float mean = s1 * 0.00390625f;
  float var = s2 * 0.00390625f - mean * mean;
  float rs = rsqrtf(var + 1e-5f);
  f32x4 gg = *(const f32x4*)(g + lane * 4);
  f32x4 bv = *(const f32x4*)(bb + lane * 4);
  ushort4v p;
#pragma unroll
  for (int i = 0; i < 4; ++i) p[i] = f2bf((v[i] - mean) * rs * gg[i] + bv[i]);
  *(ushort4v*)(out + row * 256 + lane * 4) = p;
}

extern "C" void kernel_launch(void* const* d_in, const int* in_sizes, int n_in,
                              void* d_out, int out_size, void* d_ws, size_t ws_size,
                              hipStream_t stream) {
  const float* xv = (const float*)d_in[0];
  const float* yt = (const float*)d_in[1];
  const float* pmask = (const float*)d_in[2];
  const float* prW = (const float*)d_in[3];
  const float* prb = (const float*)d_in[4];
  const float* iI = (const float*)d_in[5];
  const float* iWq = (const float*)d_in[6];
  const float* ibq = (const float*)d_in[7];
  const float* iWk = (const float*)d_in[8];
  const float* ibk = (const float*)d_in[9];
  const float* iWv = (const float*)d_in[10];
  const float* ibv = (const float*)d_in[11];
  const float* iWo = (const float*)d_in[12];
  const float* ibo = (const float*)d_in[13];
  const float* ig0 = (const float*)d_in[14];
  const float* ib0 = (const float*)d_in[15];
  const float* ig1 = (const float*)d_in[16];
  const float* ib1 = (const float*)d_in[17];
  const float* pS = (const float*)d_in[18];
  const float* pWq = (const float*)d_in[19];
  const float* pbq = (const float*)d_in[20];
  const float* pWk = (const float*)d_in[21];
  const float* pbk = (const float*)d_in[22];
  const float* pWv = (const float*)d_in[23];
  const float* pbv = (const float*)d_in[24];
  const float* pWo = (const float*)d_in[25];
  const float* pbo = (const float*)d_in[26];
  const float* pg0 = (const float*)d_in[27];
  const float* pb0 = (const float*)d_in[28];
  const float* pg1 = (const float*)d_in[29];
  const float* pb1 = (const float*)d_in[30];

  char* ws = (char*)d_ws;
  if (ws_size < 172621824u) return;
  ushort* xb = (ushort*)(ws + 0);              // 32MB (B*N x 256)
  ushort* ob = (ushort*)(ws + 33554432);       // 32MB (attn/LN scratch)
  ushort* hb = (ushort*)(ws + 67108864);       // 1MB  (B*NI x 256)
  ushort* qbw = (ushort*)(ws + 68157440);      // 32MB
  ushort* kbw = (ushort*)(ws + 101711872);     // 32MB
  ushort* vbw = (ushort*)(ws + 135266304);     // 32MB
  ushort* wt = (ushort*)(ws + 168820736);      // 3.5MB transposed weights
  ushort* q_all = (ushort*)(ws + 172490752);   // 112KB tiny-q outputs

  prep_weights<<<dim3(16, 28), 256, 0, stream>>>(iWq, iWk, iWv, iWo, pWq, pWk, pWv, pWo, wt);
  proj_gelu<<<8192, 256, 0, stream>>>(xv, yt, prW, prb, xb);
  gemm_q<<<4, 256, 0, stream>>>(iI, pS, wt, ibq, pbq, q_all);

  for (int l = 0; l < 3; ++l) {
    const int s0 = l * 2, s1 = l * 2 + 1;
    const ushort* wk = wt + (size_t)(l * 8 + 1) * 65536;
    const ushort* wv = wt + (size_t)(l * 8 + 2) * 65536;
    const ushort* wo0 = wt + (size_t)(l * 8 + 3) * 65536;
    const ushort* wq1 = wt + (size_t)(l * 8 + 4) * 65536;
    const ushort* wk1 = wt + (size_t)(l * 8 + 5) * 65536;
    const ushort* wv1 = wt + (size_t)(l * 8 + 6) * 65536;
    const ushort* wo1 = wt + (size_t)(l * 8 + 7) * 65536;
    // ---- mab0 K,V + mab1 Q: one z-merged launch; A fetched once per block ----
    gemm_bp<0, false, 3><<<512, 512, 0, stream>>>(
        xb, wk, wv, wq1, ibk + s0 * 256, ibv + s0 * 256, ibq + s1 * 256,
        kbw, vbw, qbw, nullptr, nullptr);
    attn_big<4><<<dim3(8, 32), 512, 0, stream>>>(q_all + l * 16384, kbw, vbw, pmask, ob);
    ln4<<<512, 256, 0, stream>>>(ob, ob, ig0 + s0 * 256, ib0 + s0 * 256);
    gemm_bp<3, false, 1><<<16, 512, 0, stream>>>(
        ob, wo0, wo0, wo0, ibo + s0 * 256, ibo + s0 * 256, ibo + s0 * 256,
        hb, hb, hb, ig1 + s0 * 256, ib1 + s0 * 256);
    // ---- mab1 K,V (consume hb): z-merged ----
    gemm_bp<0, false, 2><<<16, 512, 0, stream>>>(
        hb, wk1, wv1, wv1, ibk + s1 * 256, ibv + s1 * 256, ibv + s1 * 256,
        kbw, vbw, vbw, nullptr, nullptr);
    attn_small<<<dim3(32, 32), 512, 0, stream>>>(qbw, kbw, vbw, ig0 + s1 * 256, ib0 + s1 * 256, ob);
    gemm_bp<3, false, 1><<<512, 512, 0, stream>>>(
        ob, wo1, wo1, wo1, ibo + s1 * 256, ibo + s1 * 256, ibo + s1 * 256,
        xb, xb, xb, ig1 + s1 * 256, ib1 + s1 * 256);
  }
  // ---- PMA: S attends to x ----
  gemm_bp<0, false, 2><<<512, 512, 0, stream>>>(
      xb, wt + (size_t)25 * 65536, wt + (size_t)26 * 65536, wt + (size_t)26 * 65536,
      pbk, pbv, pbv, kbw, vbw, vbw, nullptr, nullptr);
  attn_big<2><<<dim3(8, 32), 512, 0, stream>>>(q_all + 49152, kbw, vbw, pmask, ob);
  ln4<<<256, 256, 0, stream>>>(ob, ob, pg0, pb0);
  gemm_bp<3, true, 1><<<8, 512, 0, stream>>>(
      ob, wt + (size_t)27 * 65536, wt + (size_t)27 * 65536, wt + (size_t)27 * 65536,
      pbo, pbo, pbo, d_out, d_out, d_out, pg1, pb1);
}

// Round 8
// 866.685 us; speedup vs baseline: 1.0941x; 1.0941x over previous
//
#include <hip/hip_runtime.h>
#include <hip/hip_bf16.h>

// SetTransformer encoder forward. B=32,N=2048,D=256,H=8,dh=32,NI=64,NL=3,NS=32.
// Round 8: revert z-merge (round-6 3072-block GEMM was faster). New mab1_fused:
// q-proj + attention + LN0 + Wo + LN1 in ONE kernel per 64-row tile (eliminates
// qbw and ob round-trips, ~190MB/layer -> ~70MB/layer).

typedef __attribute__((ext_vector_type(8))) short short8;
typedef __attribute__((ext_vector_type(4))) float f32x4;
typedef __attribute__((ext_vector_type(4))) ushort ushort4v;

__device__ __forceinline__ ushort f2bf(float f) {
  uint u = __builtin_bit_cast(uint, f);
  u += 0x7fffu + ((u >> 16) & 1u);
  return (ushort)(u >> 16);
}
__device__ __forceinline__ float bf2f(ushort h) {
  uint u = (uint)h << 16;
  return __builtin_bit_cast(float, u);
}

// ---------------- weight prep: transpose 256x256 f32 [k][n] -> bf16 [n][k] ----------------
__global__ __launch_bounds__(256) void prep_weights(
    const float* __restrict__ Wq, const float* __restrict__ Wk,
    const float* __restrict__ Wv, const float* __restrict__ Wo,
    const float* __restrict__ pWq, const float* __restrict__ pWk,
    const float* __restrict__ pWv, const float* __restrict__ pWo,
    ushort* __restrict__ wt)
{
  __shared__ float tile[64][65];
  const int m = blockIdx.y;          // 0..27
  const int t = blockIdx.x;          // 0..15
  const int tr = (t >> 2) * 64;      // k block
  const int tc = (t & 3) * 64;       // n block
  const float* src;
  if (m < 24) {
    int l = m >> 3, s = (m >> 2) & 1, w = m & 3;
    const float* base = (w == 0) ? Wq : (w == 1) ? Wk : (w == 2) ? Wv : Wo;
    src = base + (size_t)(l * 2 + s) * 65536;
  } else {
    int w = m & 3;
    src = (w == 0) ? pWq : (w == 1) ? pWk : (w == 2) ? pWv : pWo;
  }
  const int tid = threadIdx.x;
  const int cn = tid & 63;
  const int rk = tid >> 6;
#pragma unroll
  for (int j = 0; j < 16; ++j) {
    int kl = rk + j * 4;
    tile[kl][cn] = src[(size_t)(tr + kl) * 256 + tc + cn];
  }
  __syncthreads();
  ushort* dst = wt + (size_t)m * 65536;
#pragma unroll
  for (int j = 0; j < 16; ++j) {
    int nl = rk + j * 4;
    dst[(size_t)(tc + nl) * 256 + tr + cn] = f2bf(tile[cn][nl]);
  }
}

// ---------------- input projection + exact gelu -> bf16, 8 rows/block ----------------
__global__ __launch_bounds__(256) void proj_gelu(
    const float* __restrict__ xv, const float* __restrict__ yt,
    const float* __restrict__ pW, const float* __restrict__ pb,
    ushort* __restrict__ xb)
{
  const int d = threadIdx.x;
  const int row0 = blockIdx.x * 8;
  const float w0 = pW[d], w1 = pW[256 + d], w2 = pW[512 + d], w3 = pW[768 + d];
  const float bz = pb[d];
#pragma unroll
  for (int rr = 0; rr < 8; ++rr) {
    int row = row0 + rr;
    float f0 = xv[(size_t)row * 3 + 0];
    float f1 = xv[(size_t)row * 3 + 1];
    float f2 = xv[(size_t)row * 3 + 2];
    float f3 = yt[row];
    float a = bz + f0 * w0 + f1 * w1 + f2 * w2 + f3 * w3;
    float g = 0.5f * a * (1.f + erff(a * 0.70710678118654752f));
    xb[(size_t)row * 256 + d] = f2bf(g);
  }
}

// ---------------- batched tiny q-projections (f32 A, M=64/32) ----------------
__global__ __launch_bounds__(256) void gemm_q(
    const float* __restrict__ iI, const float* __restrict__ pS,
    const ushort* __restrict__ wt, const float* __restrict__ ibq,
    const float* __restrict__ pbq, ushort* __restrict__ q_all)
{
  const int bq = blockIdx.x;
  const float* A; const ushort* Wt; const float* bias; ushort* out; int M;
  if (bq < 3) { A = iI + bq * 16384; Wt = wt + (size_t)(bq * 8) * 65536; bias = ibq + bq * 512; out = q_all + bq * 16384; M = 64; }
  else        { A = pS; Wt = wt + (size_t)24 * 65536; bias = pbq; out = q_all + 49152; M = 32; }
  const int tid = threadIdx.x;
  const int wave = tid >> 6, lane = tid & 63;
  const int l15 = lane & 15, l4 = lane >> 4, koff = l4 * 8;
  f32x4 acc[4][4];
#pragma unroll
  for (int i = 0; i < 4; ++i)
#pragma unroll
    for (int j = 0; j < 4; ++j) acc[i][j] = (f32x4)0.f;
#pragma unroll
  for (int ks = 0; ks < 8; ++ks) {
    short8 af[4];
#pragma unroll
    for (int mf = 0; mf < 4; ++mf) {
      if (mf * 16 < M) {
        const float* ap = A + (size_t)(mf * 16 + l15) * 256 + ks * 32 + koff;
        float4 f0 = *(const float4*)ap;
        float4 f1 = *(const float4*)(ap + 4);
        short8 sv;
        sv[0] = (short)f2bf(f0.x); sv[1] = (short)f2bf(f0.y);
        sv[2] = (short)f2bf(f0.z); sv[3] = (short)f2bf(f0.w);
        sv[4] = (short)f2bf(f1.x); sv[5] = (short)f2bf(f1.y);
        sv[6] = (short)f2bf(f1.z); sv[7] = (short)f2bf(f1.w);
        af[mf] = sv;
      } else af[mf] = (short8)0;
    }
#pragma unroll
    for (int nf = 0; nf < 4; ++nf) {
      short8 bf = *(const short8*)(Wt + (size_t)(wave * 64 + nf * 16 + l15) * 256 + ks * 32 + koff);
#pragma unroll
      for (int mf = 0; mf < 4; ++mf)
        acc[mf][nf] = __builtin_amdgcn_mfma_f32_16x16x32_bf16(af[mf], bf, acc[mf][nf], 0, 0, 0);
    }
  }
#pragma unroll
  for (int mf = 0; mf < 4; ++mf) {
    if (mf * 16 >= M) continue;
#pragma unroll
    for (int nf = 0; nf < 4; ++nf) {
      int col = wave * 64 + nf * 16 + l15;
      float bcol = bias[col];
#pragma unroll
      for (int r = 0; r < 4; ++r)
        out[(size_t)(mf * 16 + l4 * 4 + r) * 256 + col] = f2bf(acc[mf][nf][r] + bcol);
    }
  }
}

// ---------------- B-panel GEMM (round-6 form): out = epi(A @ W + bias) ----------------
template <int EPI, bool OUTF32, int COLS>
__global__ __launch_bounds__(COLS * 2, (COLS == 128) ? 4 : 2) void gemm_bp(
    const ushort* __restrict__ A,
    const ushort* __restrict__ Wt0, const ushort* __restrict__ Wt1, const ushort* __restrict__ Wt2,
    const float* __restrict__ b0, const float* __restrict__ b1, const float* __restrict__ b2,
    void* __restrict__ o0, void* __restrict__ o1, void* __restrict__ o2,
    const float* __restrict__ lng, const float* __restrict__ lnb,
    int ny, int nyz)
{
  constexpr int WC = COLS / 64;
  constexpr int PS = COLS * 64;
  constexpr int ROWB = COLS * 2;
  __shared__ __align__(16) char Bs[4 * PS];
  __shared__ float redbuf[(EPI == 3) ? 1280 : 4];
  const int bid = blockIdx.x;
  const int bx = bid / nyz;
  const int brem = bid % nyz;
  const int y = brem % ny;
  const int z = brem / ny;
  const ushort* Wt = (z == 0) ? Wt0 : ((z == 1) ? Wt1 : Wt2);
  const float* bias = (z == 0) ? b0 : ((z == 1) ? b1 : b2);
  void* outp = (z == 0) ? o0 : ((z == 1) ? o1 : o2);
  const int pcol = y * COLS;

  const int tid = threadIdx.x;
  const int wave = tid >> 6, lane = tid & 63;
  const int wc = wave % WC, wr = wave / WC;
  const int l15 = lane & 15, l4 = lane >> 4;
  const int row0 = bx * 128;
  const int sn = tid >> 1, sseg = tid & 1;

  f32x4 acc[4][4];
#pragma unroll
  for (int i = 0; i < 4; ++i)
#pragma unroll
    for (int j = 0; j < 4; ++j) acc[i][j] = (f32x4)0.f;

#pragma unroll
  for (int half = 0; half < 2; ++half) {
    if (half) __syncthreads();
    {
      const ushort* src = Wt + (size_t)(pcol + sn) * 256 + half * 128 + sseg * 64;
#pragma unroll
      for (int c = 0; c < 8; ++c) {
        uint4 w = *(const uint4*)(src + c * 8);
        int plane = sseg * 2 + (c >> 2);
        char* dst = Bs + plane * PS + sn * 64 + (((c & 3) * 16) ^ (((sn >> 1) & 3) << 4));
        *(uint4*)dst = w;
      }
    }
    __syncthreads();
#pragma unroll
    for (int ks = 0; ks < 4; ++ks) {
      short8 af[4];
#pragma unroll
      for (int mfa = 0; mfa < 4; ++mfa)
        af[mfa] = *(const short8*)(A + (size_t)(row0 + wr * 64 + mfa * 16 + l15) * 256 + half * 128 + ks * 32 + l4 * 8);
#pragma unroll
      for (int nfb = 0; nfb < 4; ++nfb) {
        int n = wc * 64 + nfb * 16 + l15;
        short8 bf = *(const short8*)(Bs + ks * PS + n * 64 + ((l4 * 16) ^ (((n >> 1) & 3) << 4)));
#pragma unroll
        for (int mfa = 0; mfa < 4; ++mfa)
          acc[mfa][nfb] = __builtin_amdgcn_mfma_f32_16x16x32_bf16(bf, af[mfa], acc[mfa][nfb], 0, 0, 0);
      }
    }
  }

  if constexpr (EPI == 0) {
    __syncthreads();
#pragma unroll
    for (int nfb = 0; nfb < 4; ++nfb) {
      f32x4 bv = *(const f32x4*)(bias + pcol + wc * 64 + nfb * 16 + l4 * 4);
      int colb = wc * 128 + nfb * 32 + l4 * 8;
#pragma unroll
      for (int mfa = 0; mfa < 4; ++mfa) {
        int row = wr * 64 + mfa * 16 + l15;
        ushort4v pk;
#pragma unroll
        for (int i = 0; i < 4; ++i) pk[i] = f2bf(acc[mfa][nfb][i] + bv[i]);
        *(ushort4v*)(Bs + row * ROWB + (colb ^ ((row & 7) << 4))) = pk;
      }
    }
    __syncthreads();
    const int srow = tid >> 2, seg = tid & 3;
#pragma unroll
    for (int rr = 0; rr < 2; ++rr) {
      int row = srow + rr * 64;
      int x = (row & 7) << 4;
      ushort* gdst = (ushort*)outp + (size_t)(row0 + row) * 256 + pcol;
#pragma unroll
      for (int it = 0; it < 4; ++it) {
        int colb = seg * 16 + it * 64;
        uint4 v = *(const uint4*)(Bs + row * ROWB + (colb ^ x));
        *(uint4*)(gdst + colb / 2) = v;
      }
    }
  } else {
    float* red1 = redbuf;
    float* red2 = redbuf + 512;
    float* mv_ = redbuf + 1024;
    float* rv_ = redbuf + 1152;
    float s1[4] = {0.f, 0.f, 0.f, 0.f}, s2[4] = {0.f, 0.f, 0.f, 0.f};
#pragma unroll
    for (int nfb = 0; nfb < 4; ++nfb) {
      int col0 = wc * 64 + nfb * 16 + l4 * 4;
      f32x4 bv = *(const f32x4*)(bias + col0);
#pragma unroll
      for (int mfa = 0; mfa < 4; ++mfa) {
        size_t row = (size_t)row0 + wr * 64 + mfa * 16 + l15;
        ushort4v rz = *(const ushort4v*)(A + row * 256 + col0);
#pragma unroll
        for (int i = 0; i < 4; ++i) {
          float zz = bf2f(rz[i]) + fmaxf(acc[mfa][nfb][i] + bv[i], 0.f);
          acc[mfa][nfb][i] = zz;
          s1[mfa] += zz;
          s2[mfa] += zz * zz;
        }
      }
    }
#pragma unroll
    for (int mfa = 0; mfa < 4; ++mfa) {
      s1[mfa] += __shfl_xor(s1[mfa], 16); s1[mfa] += __shfl_xor(s1[mfa], 32);
      s2[mfa] += __shfl_xor(s2[mfa], 16); s2[mfa] += __shfl_xor(s2[mfa], 32);
    }
    if (l4 == 0) {
#pragma unroll
      for (int mfa = 0; mfa < 4; ++mfa) {
        red1[wc * 128 + wr * 64 + mfa * 16 + l15] = s1[mfa];
        red2[wc * 128 + wr * 64 + mfa * 16 + l15] = s2[mfa];
      }
    }
    __syncthreads();
    if (tid < 128) {
      float m1 = red1[tid] + red1[128 + tid] + red1[256 + tid] + red1[384 + tid];
      float m2 = red2[tid] + red2[128 + tid] + red2[256 + tid] + red2[384 + tid];
      float mean = m1 * 0.00390625f;
      float var = m2 * 0.00390625f - mean * mean;
      mv_[tid] = mean;
      rv_[tid] = rsqrtf(var + 1e-5f);
    }
    __syncthreads();
#pragma unroll
    for (int nfb = 0; nfb < 4; ++nfb) {
      int col0 = wc * 64 + nfb * 16 + l4 * 4;
      f32x4 gg = *(const f32x4*)(lng + col0);
      f32x4 bb = *(const f32x4*)(lnb + col0);
      int colb = col0 * 2;
#pragma unroll
      for (int mfa = 0; mfa < 4; ++mfa) {
        int lr = wr * 64 + mfa * 16 + l15;
        float mean = mv_[lr], rs = rv_[lr];
        if constexpr (OUTF32) {
          f32x4 w;
#pragma unroll
          for (int i = 0; i < 4; ++i) w[i] = (acc[mfa][nfb][i] - mean) * rs * gg[i] + bb[i];
          *(f32x4*)((float*)outp + ((size_t)row0 + lr) * 256 + col0) = w;
        } else {
          ushort4v pk;
#pragma unroll
          for (int i = 0; i < 4; ++i) pk[i] = f2bf((acc[mfa][nfb][i] - mean) * rs * gg[i] + bb[i]);
          *(ushort4v*)(Bs + lr * ROWB + (colb ^ ((lr & 7) << 4))) = pk;
        }
      }
    }
    if constexpr (!OUTF32) {
      __syncthreads();
      const int srow = tid >> 2, seg = tid & 3;
      int x = (srow & 7) << 4;
      ushort* gdst = (ushort*)outp + (size_t)(row0 + srow) * 256;
#pragma unroll
      for (int it = 0; it < 8; ++it) {
        int colb = seg * 16 + it * 64;
        uint4 v = *(const uint4*)(Bs + srow * ROWB + (colb ^ x));
        *(uint4*)(gdst + colb / 2) = v;
      }
    }
  }
}

// ---------------- attn_big: nq small (64/32), nk=2048, masked, q shared across batch ----
template <int MF>
__global__ __launch_bounds__(512) void attn_big(
    const ushort* __restrict__ qb, const ushort* __restrict__ kb,
    const ushort* __restrict__ vb, const float* __restrict__ mask,
    ushort* __restrict__ O)
{
  __shared__ __align__(16) ushort Ps[8][64][72];
  __shared__ __align__(16) ushort Vt[8][32][72];
  const int h = blockIdx.x, b = blockIdx.y;
  const int tid = threadIdx.x;
  const int w = tid >> 6, lane = tid & 63;
  const int l15 = lane & 15, l4 = lane >> 4;
  const int koff = l4 * 8;
  const int kvbase = b * 2048;

  short8 qf[MF];
#pragma unroll
  for (int mf = 0; mf < MF; ++mf)
    qf[mf] = *(const short8*)(qb + (size_t)(mf * 16 + l15) * 256 + h * 32 + koff);

  f32x4 Oa[MF][2];
  float Mr[MF][4], Lr[MF][4];
#pragma unroll
  for (int mf = 0; mf < MF; ++mf) {
    Oa[mf][0] = (f32x4)0.f; Oa[mf][1] = (f32x4)0.f;
#pragma unroll
    for (int r = 0; r < 4; ++r) { Mr[mf][r] = -1e30f; Lr[mf][r] = 0.f; }
  }

  for (int c = 0; c < 4; ++c) {
    const int kc = w * 256 + c * 64;
    f32x4 S[MF][4];
#pragma unroll
    for (int nf = 0; nf < 4; ++nf) {
      short8 kf = *(const short8*)(kb + (size_t)(kvbase + kc + nf * 16 + l15) * 256 + h * 32 + koff);
#pragma unroll
      for (int mf = 0; mf < MF; ++mf)
        S[mf][nf] = __builtin_amdgcn_mfma_f32_16x16x32_bf16(qf[mf], kf, (f32x4)0.f, 0, 0, 0);
    }
    float mv[4];
#pragma unroll
    for (int nf = 0; nf < 4; ++nf)
      mv[nf] = mask[(size_t)b * 2048 + kc + nf * 16 + l15];
#pragma unroll
    for (int mf = 0; mf < MF; ++mf)
#pragma unroll
      for (int nf = 0; nf < 4; ++nf)
#pragma unroll
        for (int r = 0; r < 4; ++r) {
          float s = S[mf][nf][r] * 0.0625f;
          S[mf][nf][r] = (mv[nf] != 0.f) ? s : -1e4f;
        }
#pragma unroll
    for (int mf = 0; mf < MF; ++mf)
#pragma unroll
      for (int r = 0; r < 4; ++r) {
        float pm = fmaxf(fmaxf(S[mf][0][r], S[mf][1][r]), fmaxf(S[mf][2][r], S[mf][3][r]));
        pm = fmaxf(pm, __shfl_xor(pm, 1));
        pm = fmaxf(pm, __shfl_xor(pm, 2));
        pm = fmaxf(pm, __shfl_xor(pm, 4));
        pm = fmaxf(pm, __shfl_xor(pm, 8));
        float Mnew = fmaxf(Mr[mf][r], pm);
        float corr = __expf(Mr[mf][r] - Mnew);
        Mr[mf][r] = Mnew;
        float rs = 0.f;
#pragma unroll
        for (int nf = 0; nf < 4; ++nf) {
          float p = __expf(S[mf][nf][r] - Mnew);
          S[mf][nf][r] = p;
          rs += p;
        }
        rs += __shfl_xor(rs, 1);
        rs += __shfl_xor(rs, 2);
        rs += __shfl_xor(rs, 4);
        rs += __shfl_xor(rs, 8);
        Lr[mf][r] = Lr[mf][r] * corr + rs;
        Oa[mf][0][r] *= corr;
        Oa[mf][1][r] *= corr;
      }
#pragma unroll
    for (int dblk = 0; dblk < 4; ++dblk) {
      short8 vv = *(const short8*)(vb + (size_t)(kvbase + kc + lane) * 256 + h * 32 + dblk * 8);
#pragma unroll
      for (int j = 0; j < 8; ++j) Vt[w][dblk * 8 + j][lane] = (ushort)vv[j];
    }
#pragma unroll
    for (int mf = 0; mf < MF; ++mf)
#pragma unroll
      for (int nf = 0; nf < 4; ++nf)
#pragma unroll
        for (int r = 0; r < 4; ++r)
          Ps[w][mf * 16 + l4 * 4 + r][nf * 16 + l15] = f2bf(S[mf][nf][r]);
#pragma unroll
    for (int ks = 0; ks < 2; ++ks) {
      short8 pf[MF];
#pragma unroll
      for (int mf = 0; mf < MF; ++mf)
        pf[mf] = *(const short8*)&Ps[w][mf * 16 + l15][ks * 32 + koff];
#pragma unroll
      for (int nf2 = 0; nf2 < 2; ++nf2) {
        short8 vf = *(const short8*)&Vt[w][nf2 * 16 + l15][ks * 32 + koff];
#pragma unroll
        for (int mf = 0; mf < MF; ++mf)
          Oa[mf][nf2] = __builtin_amdgcn_mfma_f32_16x16x32_bf16(pf[mf], vf, Oa[mf][nf2], 0, 0, 0);
      }
    }
  }

  __syncthreads();
  float* Mw = (float*)&Ps[0][0][0];
  float* Lw = Mw + 512;
  float* Ow = Lw + 512;  // [8][64][33]
#pragma unroll
  for (int mf = 0; mf < MF; ++mf)
#pragma unroll
    for (int r = 0; r < 4; ++r) {
      int row = mf * 16 + l4 * 4 + r;
      if (l15 == 0) { Mw[w * 64 + row] = Mr[mf][r]; Lw[w * 64 + row] = Lr[mf][r]; }
#pragma unroll
      for (int nf2 = 0; nf2 < 2; ++nf2)
        Ow[(w * 64 + row) * 33 + nf2 * 16 + l15] = Oa[mf][nf2][r];
    }
  __syncthreads();
  const int NQ = MF * 16;
  int row = tid >> 3, dg = tid & 7;
  if (row < NQ) {
    float mm = -1e30f;
#pragma unroll
    for (int s = 0; s < 8; ++s) mm = fmaxf(mm, Mw[s * 64 + row]);
    float den = 0.f, es[8];
#pragma unroll
    for (int s = 0; s < 8; ++s) {
      es[s] = __expf(Mw[s * 64 + row] - mm);
      den += Lw[s * 64 + row] * es[s];
    }
    float invden = 1.f / den;
    ushort4v pk;
#pragma unroll
    for (int i = 0; i < 4; ++i) {
      int d = dg * 4 + i;
      float num = 0.f;
#pragma unroll
      for (int s = 0; s < 8; ++s) num += Ow[(s * 64 + row) * 33 + d] * es[s];
      float qv = bf2f(qb[(size_t)row * 256 + h * 32 + d]);
      pk[i] = f2bf(qv + num * invden);
    }
    *(ushort4v*)(O + (size_t)(b * NQ + row) * 256 + h * 32 + dg * 4) = pk;
  }
}

// ---------------- mab1_fused: q-proj + attention(nk=64) + LN0 + Wo + LN1 ----------------
// grid(qt=32, b=32), block 512 = 8 waves = 8 heads over the same 64 q-rows.
// Reads xb rows (q-GEMM A), kb/vb (small), Wq/Wo direct from L2. Writes xb rows in-place.
__global__ __launch_bounds__(512, 1) void mab1_fused(
    const ushort* __restrict__ xb, const ushort* __restrict__ wq,
    const float* __restrict__ bq,
    const ushort* __restrict__ kb, const ushort* __restrict__ vb,
    const ushort* __restrict__ wo, const float* __restrict__ bo,
    const float* __restrict__ g0, const float* __restrict__ b0v,
    const float* __restrict__ g1, const float* __restrict__ b1v,
    ushort* __restrict__ outb)
{
  __shared__ __align__(16) ushort Qs[8][64][40];   // 40KB: q tiles, wave-private
  __shared__ __align__(16) ushort Ps[8][64][72];   // 72KB: P tiles; later o_s[64][264]
  __shared__ __align__(16) ushort Vt[8][32][72];   // 36KB: V^T tiles
  __shared__ float red1[8][64], red2[8][64], mv_[64], rv_[64];
  ushort* o_s = &Ps[0][0][0];
  constexpr int OS = 264;

  const int qt = blockIdx.x, b = blockIdx.y;
  const int tid = threadIdx.x;
  const int w = tid >> 6, lane = tid & 63;  // w = head / col-group
  const int l15 = lane & 15, l4 = lane >> 4;
  const int koff = l4 * 8;
  const size_t row0 = (size_t)b * 2048 + qt * 64;
  const int kvbase = b * 64;
  const int h = w;

  // ---- phase 1: q[64][32] (head w) = xb[rows] @ Wq[:, w*32..] + bq -> Qs (bf16) ----
  {
    f32x4 qa[4][2];
#pragma unroll
    for (int i = 0; i < 4; ++i) { qa[i][0] = (f32x4)0.f; qa[i][1] = (f32x4)0.f; }
#pragma unroll
    for (int ks = 0; ks < 8; ++ks) {
      short8 af[4];
#pragma unroll
      for (int mfa = 0; mfa < 4; ++mfa)
        af[mfa] = *(const short8*)(xb + (row0 + mfa * 16 + l15) * 256 + ks * 32 + koff);
#pragma unroll
      for (int nfb = 0; nfb < 2; ++nfb) {
        int n = w * 32 + nfb * 16 + l15;
        short8 bf = *(const short8*)(wq + (size_t)n * 256 + ks * 32 + koff);
#pragma unroll
        for (int mfa = 0; mfa < 4; ++mfa)  // swapped: D row<-l15(A row), col<-l4*4+i (n)
          qa[mfa][nfb] = __builtin_amdgcn_mfma_f32_16x16x32_bf16(bf, af[mfa], qa[mfa][nfb], 0, 0, 0);
      }
    }
#pragma unroll
    for (int nfb = 0; nfb < 2; ++nfb) {
      f32x4 bv = *(const f32x4*)(bq + w * 32 + nfb * 16 + l4 * 4);
#pragma unroll
      for (int mfa = 0; mfa < 4; ++mfa) {
        ushort4v pk;
#pragma unroll
        for (int i = 0; i < 4; ++i) pk[i] = f2bf(qa[mfa][nfb][i] + bv[i]);
        *(ushort4v*)&Qs[w][mfa * 16 + l15][nfb * 16 + l4 * 4] = pk;
      }
    }
  }

  // ---- phase 2: attention (attn_small pattern, q from Qs) ----
  short8 qf[4];
#pragma unroll
  for (int mf = 0; mf < 4; ++mf)
    qf[mf] = *(const short8*)&Qs[w][mf * 16 + l15][koff];

  f32x4 S[4][4];
#pragma unroll
  for (int nf = 0; nf < 4; ++nf) {
    short8 kf = *(const short8*)(kb + (size_t)(kvbase + nf * 16 + l15) * 256 + h * 32 + koff);
#pragma unroll
    for (int mf = 0; mf < 4; ++mf)
      S[mf][nf] = __builtin_amdgcn_mfma_f32_16x16x32_bf16(qf[mf], kf, (f32x4)0.f, 0, 0, 0);
  }
  float Lr[4][4];
#pragma unroll
  for (int mf = 0; mf < 4; ++mf)
#pragma unroll
    for (int r = 0; r < 4; ++r) {
      float pm = fmaxf(fmaxf(S[mf][0][r], S[mf][1][r]), fmaxf(S[mf][2][r], S[mf][3][r])) * 0.0625f;
      pm = fmaxf(pm, __shfl_xor(pm, 1));
      pm = fmaxf(pm, __shfl_xor(pm, 2));
      pm = fmaxf(pm, __shfl_xor(pm, 4));
      pm = fmaxf(pm, __shfl_xor(pm, 8));
      float rs = 0.f;
#pragma unroll
      for (int nf = 0; nf < 4; ++nf) {
        float p = __expf(S[mf][nf][r] * 0.0625f - pm);
        S[mf][nf][r] = p;
        rs += p;
      }
      rs += __shfl_xor(rs, 1);
      rs += __shfl_xor(rs, 2);
      rs += __shfl_xor(rs, 4);
      rs += __shfl_xor(rs, 8);
      Lr[mf][r] = rs;
    }
#pragma unroll
  for (int dblk = 0; dblk < 4; ++dblk) {
    short8 vv = *(const short8*)(vb + (size_t)(kvbase + lane) * 256 + h * 32 + dblk * 8);
#pragma unroll
    for (int j = 0; j < 8; ++j) Vt[w][dblk * 8 + j][lane] = (ushort)vv[j];
  }
#pragma unroll
  for (int mf = 0; mf < 4; ++mf)
#pragma unroll
    for (int nf = 0; nf < 4; ++nf)
#pragma unroll
      for (int r = 0; r < 4; ++r)
        Ps[w][mf * 16 + l4 * 4 + r][nf * 16 + l15] = f2bf(S[mf][nf][r]);
  f32x4 Oa[4][2];
#pragma unroll
  for (int mf = 0; mf < 4; ++mf) { Oa[mf][0] = (f32x4)0.f; Oa[mf][1] = (f32x4)0.f; }
#pragma unroll
  for (int ks = 0; ks < 2; ++ks) {
    short8 pf[4];
#pragma unroll
    for (int mf = 0; mf < 4; ++mf)
      pf[mf] = *(const short8*)&Ps[w][mf * 16 + l15][ks * 32 + koff];
#pragma unroll
    for (int nf2 = 0; nf2 < 2; ++nf2) {
      short8 vf = *(const short8*)&Vt[w][nf2 * 16 + l15][ks * 32 + koff];
#pragma unroll
      for (int mf = 0; mf < 4; ++mf)
        Oa[mf][nf2] = __builtin_amdgcn_mfma_f32_16x16x32_bf16(pf[mf], vf, Oa[mf][nf2], 0, 0, 0);
    }
  }

  // ---- phase 3: o = q + PV/L; LN0 stats ----
  {
    float s1[4][4], s2[4][4];
#pragma unroll
    for (int mf = 0; mf < 4; ++mf)
#pragma unroll
      for (int r = 0; r < 4; ++r) {
        float invL = 1.f / Lr[mf][r];
        s1[mf][r] = 0.f; s2[mf][r] = 0.f;
#pragma unroll
        for (int nf2 = 0; nf2 < 2; ++nf2) {
          float qv = bf2f(Qs[w][mf * 16 + l4 * 4 + r][nf2 * 16 + l15]);
          float z = qv + Oa[mf][nf2][r] * invL;
          Oa[mf][nf2][r] = z;
          s1[mf][r] += z;
          s2[mf][r] += z * z;
        }
#pragma unroll
        for (int off = 1; off < 16; off <<= 1) {
          s1[mf][r] += __shfl_xor(s1[mf][r], off);
          s2[mf][r] += __shfl_xor(s2[mf][r], off);
        }
        if (l15 == 0) {
          int row = mf * 16 + l4 * 4 + r;
          red1[w][row] = s1[mf][r];
          red2[w][row] = s2[mf][r];
        }
      }
  }
  __syncthreads();  // all waves past PV (Ps/Vt dead); red1/red2 complete
  if (tid < 64) {
    float m1 = 0.f, m2 = 0.f;
#pragma unroll
    for (int s = 0; s < 8; ++s) { m1 += red1[s][tid]; m2 += red2[s][tid]; }
    float mean = m1 * 0.00390625f;
    float var = m2 * 0.00390625f - mean * mean;
    mv_[tid] = mean;
    rv_[tid] = rsqrtf(var + 1e-5f);
  }
  __syncthreads();
  // apply LN0 -> o_s (overlay on Ps)
#pragma unroll
  for (int nf2 = 0; nf2 < 2; ++nf2) {
    int col = h * 32 + nf2 * 16 + l15;
    float gc = g0[col], bc = b0v[col];
#pragma unroll
    for (int mf = 0; mf < 4; ++mf)
#pragma unroll
      for (int r = 0; r < 4; ++r) {
        int row = mf * 16 + l4 * 4 + r;
        float v = (Oa[mf][nf2][r] - mv_[row]) * rv_[row] * gc + bc;
        o_s[row * OS + col] = f2bf(v);
      }
  }
  __syncthreads();

  // ---- phase 4: Wo GEMM (cols w*32..) + resid + LN1 ----
  f32x4 oa[4][2];
#pragma unroll
  for (int i = 0; i < 4; ++i) { oa[i][0] = (f32x4)0.f; oa[i][1] = (f32x4)0.f; }
#pragma unroll
  for (int ks = 0; ks < 8; ++ks) {
    short8 af[4];
#pragma unroll
    for (int mfa = 0; mfa < 4; ++mfa)
      af[mfa] = *(const short8*)&o_s[(mfa * 16 + l15) * OS + ks * 32 + koff];
#pragma unroll
    for (int nfb = 0; nfb < 2; ++nfb) {
      int n = w * 32 + nfb * 16 + l15;
      short8 bf = *(const short8*)(wo + (size_t)n * 256 + ks * 32 + koff);
#pragma unroll
      for (int mfa = 0; mfa < 4; ++mfa)
        oa[mfa][nfb] = __builtin_amdgcn_mfma_f32_16x16x32_bf16(bf, af[mfa], oa[mfa][nfb], 0, 0, 0);
    }
  }
  float t1[4] = {0.f, 0.f, 0.f, 0.f}, t2[4] = {0.f, 0.f, 0.f, 0.f};
#pragma unroll
  for (int nfb = 0; nfb < 2; ++nfb) {
    int col0 = w * 32 + nfb * 16 + l4 * 4;
    f32x4 bv = *(const f32x4*)(bo + col0);
#pragma unroll
    for (int mfa = 0; mfa < 4; ++mfa) {
      int row = mfa * 16 + l15;
      ushort4v rz = *(const ushort4v*)&o_s[row * OS + col0];
#pragma unroll
      for (int i = 0; i < 4; ++i) {
        float zz = bf2f(rz[i]) + fmaxf(oa[mfa][nfb][i] + bv[i], 0.f);
        oa[mfa][nfb][i] = zz;
        t1[mfa] += zz;
        t2[mfa] += zz * zz;
      }
    }
  }
#pragma unroll
  for (int mfa = 0; mfa < 4; ++mfa) {
    t1[mfa] += __shfl_xor(t1[mfa], 16); t1[mfa] += __shfl_xor(t1[mfa], 32);
    t2[mfa] += __shfl_xor(t2[mfa], 16); t2[mfa] += __shfl_xor(t2[mfa], 32);
  }
  if (l4 == 0) {
#pragma unroll
    for (int mfa = 0; mfa < 4; ++mfa) {
      red1[w][mfa * 16 + l15] = t1[mfa];
      red2[w][mfa * 16 + l15] = t2[mfa];
    }
  }
  __syncthreads();
  if (tid < 64) {
    float m1 = 0.f, m2 = 0.f;
#pragma unroll
    for (int s = 0; s < 8; ++s) { m1 += red1[s][tid]; m2 += red2[s][tid]; }
    float mean = m1 * 0.00390625f;
    float var = m2 * 0.00390625f - mean * mean;
    mv_[tid] = mean;
    rv_[tid] = rsqrtf(var + 1e-5f);
  }
  __syncthreads();
#pragma unroll
  for (int nfb = 0; nfb < 2; ++nfb) {
    int col0 = w * 32 + nfb * 16 + l4 * 4;
    f32x4 gg = *(const f32x4*)(g1 + col0);
    f32x4 bb = *(const f32x4*)(b1v + col0);
#pragma unroll
    for (int mfa = 0; mfa < 4; ++mfa) {
      int row = mfa * 16 + l15;
      ushort4v pk;
#pragma unroll
      for (int i = 0; i < 4; ++i)
        pk[i] = f2bf((oa[mfa][nfb][i] - mv_[row]) * rv_[row] * gg[i] + bb[i]);
      *(ushort4v*)&o_s[row * OS + col0] = pk;  // per-lane same addr as resid read: safe
    }
  }
  __syncthreads();
  // cooperative full-line store: 512 thr -> 64 rows x 8 segs of 64B
  {
    const int r_ = tid >> 3, sg = tid & 7;
    ushort* gdst = outb + (row0 + r_) * 256 + sg * 32;
    const ushort* src = &o_s[r_ * OS + sg * 32];
#pragma unroll
    for (int it = 0; it < 4; ++it) {
      uint4 v = *(const uint4*)(src + it * 8);
      *(uint4*)(gdst + it * 8) = v;
    }
  }
}

// ---------------- small LayerNorm: bf16 in/out, wave per row ----------------
__global__ __launch_bounds__(256) void ln4(
    const ushort* __restrict__ in, ushort* __restrict__ out,
    const float* __restrict__ g, const float* __restrict__ bb)
{
  const int w = threadIdx.x >> 6, lane = threadIdx.x & 63;
  const size_t row = (size_t)blockIdx.x * 4 + w;
  ushort4v u = *(const ushort4v*)(in + row * 256 + lane * 4);
  float v[4];
#pragma unroll
  for (int i = 0; i < 4; ++i) v[i] = bf2f(u[i]);
  float s1 = v[0] + v[1] + v[2] + v[3];
  float s2 = v[0] * v[0] + v[1] * v[1] + v[2] * v[2] + v[3] * v[3];
#pragma unroll
  for (int off = 1; off < 64; off <<= 1) {
    s1 += __shfl_xor(s1, off);
    s2 += __shfl_xor(s2, off);
  }
  float mean = s1 * 0.00390625f;
  float var = s2 * 0.00390625f - mean * mean;
  float rs = rsqrtf(var + 1e-5f);
  f32x4 gg = *(const f32x4*)(g + lane * 4);
  f32x4 bv = *(const f32x4*)(bb + lane * 4);
  ushort4v p;
#pragma unroll
  for (int i = 0; i < 4; ++i) p[i] = f2bf((v[i] - mean) * rs * gg[i] + bv[i]);
  *(ushort4v*)(out + row * 256 + lane * 4) = p;
}

extern "C" void kernel_launch(void* const* d_in, const int* in_sizes, int n_in,
                              void* d_out, int out_size, void* d_ws, size_t ws_size,
                              hipStream_t stream) {
  const float* xv = (const float*)d_in[0];
  const float* yt = (const float*)d_in[1];
  const float* pmask = (const float*)d_in[2];
  const float* prW = (const float*)d_in[3];
  const float* prb = (const float*)d_in[4];
  const float* iI = (const float*)d_in[5];
  const float* iWq = (const float*)d_in[6];
  const float* ibq = (const float*)d_in[7];
  const float* iWk = (const float*)d_in[8];
  const float* ibk = (const float*)d_in[9];
  const float* iWv = (const float*)d_in[10];
  const float* ibv = (const float*)d_in[11];
  const float* iWo = (const float*)d_in[12];
  const float* ibo = (const float*)d_in[13];
  const float* ig0 = (const float*)d_in[14];
  const float* ib0 = (const float*)d_in[15];
  const float* ig1 = (const float*)d_in[16];
  const float* ib1 = (const float*)d_in[17];
  const float* pS = (const float*)d_in[18];
  const float* pWq = (const float*)d_in[19];
  const float* pbq = (const float*)d_in[20];
  const float* pWk = (const float*)d_in[21];
  const float* pbk = (const float*)d_in[22];
  const float* pWv = (const float*)d_in[23];
  const float* pbv = (const float*)d_in[24];
  const float* pWo = (const float*)d_in[25];
  const float* pbo = (const float*)d_in[26];
  const float* pg0 = (const float*)d_in[27];
  const float* pb0 = (const float*)d_in[28];
  const float* pg1 = (const float*)d_in[29];
  const float* pb1 = (const float*)d_in[30];

  char* ws = (char*)d_ws;
  if (ws_size < 172621824u) return;
  ushort* xb = (ushort*)(ws + 0);              // 32MB (B*N x 256)
  ushort* ob = (ushort*)(ws + 33554432);       // 32MB (attn/LN scratch)
  ushort* hb = (ushort*)(ws + 67108864);       // 1MB  (B*NI x 256)
  ushort* kbw = (ushort*)(ws + 101711872);     // 32MB
  ushort* vbw = (ushort*)(ws + 135266304);     // 32MB
  ushort* wt = (ushort*)(ws + 168820736);      // 3.5MB transposed weights
  ushort* q_all = (ushort*)(ws + 172490752);   // 112KB tiny-q outputs

  prep_weights<<<dim3(16, 28), 256, 0, stream>>>(iWq, iWk, iWv, iWo, pWq, pWk, pWv, pWo, wt);
  proj_gelu<<<8192, 256, 0, stream>>>(xv, yt, prW, prb, xb);
  gemm_q<<<4, 256, 0, stream>>>(iI, pS, wt, ibq, pbq, q_all);

  for (int l = 0; l < 3; ++l) {
    const int s0 = l * 2, s1 = l * 2 + 1;
    const ushort* wk = wt + (size_t)(l * 8 + 1) * 65536;
    const ushort* wv = wt + (size_t)(l * 8 + 2) * 65536;
    const ushort* wo0 = wt + (size_t)(l * 8 + 3) * 65536;
    const ushort* wq1 = wt + (size_t)(l * 8 + 4) * 65536;
    const ushort* wk1 = wt + (size_t)(l * 8 + 5) * 65536;
    const ushort* wv1 = wt + (size_t)(l * 8 + 6) * 65536;
    const ushort* wo1 = wt + (size_t)(l * 8 + 7) * 65536;
    // ---- mab0 K,V (consume xb): batched, sharers consecutive ----
    gemm_bp<0, false, 128><<<2048, 256, 0, stream>>>(
        xb, wk, wv, wv, ibk + s0 * 256, ibv + s0 * 256, ibv + s0 * 256,
        kbw, vbw, vbw, nullptr, nullptr, 2, 4);
    attn_big<4><<<dim3(8, 32), 512, 0, stream>>>(q_all + l * 16384, kbw, vbw, pmask, ob);
    ln4<<<512, 256, 0, stream>>>(ob, ob, ig0 + s0 * 256, ib0 + s0 * 256);
    gemm_bp<3, false, 256><<<16, 512, 0, stream>>>(
        ob, wo0, wo0, wo0, ibo + s0 * 256, ibo + s0 * 256, ibo + s0 * 256,
        hb, hb, hb, ig1 + s0 * 256, ib1 + s0 * 256, 1, 1);
    // ---- mab1 K,V (consume hb) ----
    gemm_bp<0, false, 128><<<64, 256, 0, stream>>>(
        hb, wk1, wv1, wv1, ibk + s1 * 256, ibv + s1 * 256, ibv + s1 * 256,
        kbw, vbw, vbw, nullptr, nullptr, 2, 4);
    // ---- mab1 fused: q-proj + attention + LN0 + Wo + LN1, xb in-place ----
    mab1_fused<<<dim3(32, 32), 512, 0, stream>>>(
        xb, wq1, ibq + s1 * 256, kbw, vbw, wo1, ibo + s1 * 256,
        ig0 + s1 * 256, ib0 + s1 * 256, ig1 + s1 * 256, ib1 + s1 * 256, xb);
  }
  // ---- PMA: S attends to x ----
  gemm_bp<0, false, 128><<<2048, 256, 0, stream>>>(
      xb, wt + (size_t)25 * 65536, wt + (size_t)26 * 65536, wt + (size_t)26 * 65536,
      pbk, pbv, pbv, kbw, vbw, vbw, nullptr, nullptr, 2, 4);
  attn_big<2><<<dim3(8, 32), 512, 0, stream>>>(q_all + 49152, kbw, vbw, pmask, ob);
  ln4<<<256, 256, 0, stream>>>(ob, ob, pg0, pb0);
  gemm_bp<3, true, 256><<<8, 512, 0, stream>>>(
      ob, wt + (size_t)27 * 65536, wt + (size_t)27 * 65536, wt + (size_t)27 * 65536,
      pbo, pbo, pbo, d_out, d_out, d_out, pg1, pb1, 1, 1);
}

// Round 9
// 853.003 us; speedup vs baseline: 1.1117x; 1.0160x over previous
//
#include <hip/hip_runtime.h>
#include <hip/hip_bf16.h>

// SetTransformer encoder forward. B=32,N=2048,D=256,H=8,dh=32,NI=64,NL=3,NS=32.
// Round 9: (1) XCD-colocating dispatch swizzle in gemm_bp (A-panel sharers -> same
// XCD L2, bid%8 invariant); (2) mab1_fused deep prefetch (Vt staging, K frags, and
// full Wo B-fragment preload hoisted to kernel entry to hide L2 latency).

typedef __attribute__((ext_vector_type(8))) short short8;
typedef __attribute__((ext_vector_type(4))) float f32x4;
typedef __attribute__((ext_vector_type(4))) ushort ushort4v;

__device__ __forceinline__ ushort f2bf(float f) {
  uint u = __builtin_bit_cast(uint, f);
  u += 0x7fffu + ((u >> 16) & 1u);
  return (ushort)(u >> 16);
}
__device__ __forceinline__ float bf2f(ushort h) {
  uint u = (uint)h << 16;
  return __builtin_bit_cast(float, u);
}

// ---------------- weight prep: transpose 256x256 f32 [k][n] -> bf16 [n][k] ----------------
__global__ __launch_bounds__(256) void prep_weights(
    const float* __restrict__ Wq, const float* __restrict__ Wk,
    const float* __restrict__ Wv, const float* __restrict__ Wo,
    const float* __restrict__ pWq, const float* __restrict__ pWk,
    const float* __restrict__ pWv, const float* __restrict__ pWo,
    ushort* __restrict__ wt)
{
  __shared__ float tile[64][65];
  const int m = blockIdx.y;          // 0..27
  const int t = blockIdx.x;          // 0..15
  const int tr = (t >> 2) * 64;      // k block
  const int tc = (t & 3) * 64;       // n block
  const float* src;
  if (m < 24) {
    int l = m >> 3, s = (m >> 2) & 1, w = m & 3;
    const float* base = (w == 0) ? Wq : (w == 1) ? Wk : (w == 2) ? Wv : Wo;
    src = base + (size_t)(l * 2 + s) * 65536;
  } else {
    int w = m & 3;
    src = (w == 0) ? pWq : (w == 1) ? pWk : (w == 2) ? pWv : pWo;
  }
  const int tid = threadIdx.x;
  const int cn = tid & 63;
  const int rk = tid >> 6;
#pragma unroll
  for (int j = 0; j < 16; ++j) {
    int kl = rk + j * 4;
    tile[kl][cn] = src[(size_t)(tr + kl) * 256 + tc + cn];
  }
  __syncthreads();
  ushort* dst = wt + (size_t)m * 65536;
#pragma unroll
  for (int j = 0; j < 16; ++j) {
    int nl = rk + j * 4;
    dst[(size_t)(tc + nl) * 256 + tr + cn] = f2bf(tile[cn][nl]);
  }
}

// ---------------- input projection + exact gelu -> bf16, 8 rows/block ----------------
__global__ __launch_bounds__(256) void proj_gelu(
    const float* __restrict__ xv, const float* __restrict__ yt,
    const float* __restrict__ pW, const float* __restrict__ pb,
    ushort* __restrict__ xb)
{
  const int d = threadIdx.x;
  const int row0 = blockIdx.x * 8;
  const float w0 = pW[d], w1 = pW[256 + d], w2 = pW[512 + d], w3 = pW[768 + d];
  const float bz = pb[d];
#pragma unroll
  for (int rr = 0; rr < 8; ++rr) {
    int row = row0 + rr;
    float f0 = xv[(size_t)row * 3 + 0];
    float f1 = xv[(size_t)row * 3 + 1];
    float f2 = xv[(size_t)row * 3 + 2];
    float f3 = yt[row];
    float a = bz + f0 * w0 + f1 * w1 + f2 * w2 + f3 * w3;
    float g = 0.5f * a * (1.f + erff(a * 0.70710678118654752f));
    xb[(size_t)row * 256 + d] = f2bf(g);
  }
}

// ---------------- batched tiny q-projections (f32 A, M=64/32) ----------------
__global__ __launch_bounds__(256) void gemm_q(
    const float* __restrict__ iI, const float* __restrict__ pS,
    const ushort* __restrict__ wt, const float* __restrict__ ibq,
    const float* __restrict__ pbq, ushort* __restrict__ q_all)
{
  const int bq = blockIdx.x;
  const float* A; const ushort* Wt; const float* bias; ushort* out; int M;
  if (bq < 3) { A = iI + bq * 16384; Wt = wt + (size_t)(bq * 8) * 65536; bias = ibq + bq * 512; out = q_all + bq * 16384; M = 64; }
  else        { A = pS; Wt = wt + (size_t)24 * 65536; bias = pbq; out = q_all + 49152; M = 32; }
  const int tid = threadIdx.x;
  const int wave = tid >> 6, lane = tid & 63;
  const int l15 = lane & 15, l4 = lane >> 4, koff = l4 * 8;
  f32x4 acc[4][4];
#pragma unroll
  for (int i = 0; i < 4; ++i)
#pragma unroll
    for (int j = 0; j < 4; ++j) acc[i][j] = (f32x4)0.f;
#pragma unroll
  for (int ks = 0; ks < 8; ++ks) {
    short8 af[4];
#pragma unroll
    for (int mf = 0; mf < 4; ++mf) {
      if (mf * 16 < M) {
        const float* ap = A + (size_t)(mf * 16 + l15) * 256 + ks * 32 + koff;
        float4 f0 = *(const float4*)ap;
        float4 f1 = *(const float4*)(ap + 4);
        short8 sv;
        sv[0] = (short)f2bf(f0.x); sv[1] = (short)f2bf(f0.y);
        sv[2] = (short)f2bf(f0.z); sv[3] = (short)f2bf(f0.w);
        sv[4] = (short)f2bf(f1.x); sv[5] = (short)f2bf(f1.y);
        sv[6] = (short)f2bf(f1.z); sv[7] = (short)f2bf(f1.w);
        af[mf] = sv;
      } else af[mf] = (short8)0;
    }
#pragma unroll
    for (int nf = 0; nf < 4; ++nf) {
      short8 bf = *(const short8*)(Wt + (size_t)(wave * 64 + nf * 16 + l15) * 256 + ks * 32 + koff);
#pragma unroll
      for (int mf = 0; mf < 4; ++mf)
        acc[mf][nf] = __builtin_amdgcn_mfma_f32_16x16x32_bf16(af[mf], bf, acc[mf][nf], 0, 0, 0);
    }
  }
#pragma unroll
  for (int mf = 0; mf < 4; ++mf) {
    if (mf * 16 >= M) continue;
#pragma unroll
    for (int nf = 0; nf < 4; ++nf) {
      int col = wave * 64 + nf * 16 + l15;
      float bcol = bias[col];
#pragma unroll
      for (int r = 0; r < 4; ++r)
        out[(size_t)(mf * 16 + l4 * 4 + r) * 256 + col] = f2bf(acc[mf][nf][r] + bcol);
    }
  }
}

// ---------------- B-panel GEMM: out = epi(A @ W + bias) ----------------
// 1-D grid with XCD-colocating decode: bid = (x&7) + 8*(yz + nyz*(x>>3)), so the
// nyz A-panel sharers of x share bid%8 (same XCD L2) and are adjacent in that
// XCD's dispatch stream. Identity when nyz==1. Grid must be 8*nyz*ceil(M/128/8).
template <int EPI, bool OUTF32, int COLS>
__global__ __launch_bounds__(COLS * 2, (COLS == 128) ? 4 : 2) void gemm_bp(
    const ushort* __restrict__ A,
    const ushort* __restrict__ Wt0, const ushort* __restrict__ Wt1, const ushort* __restrict__ Wt2,
    const float* __restrict__ b0, const float* __restrict__ b1, const float* __restrict__ b2,
    void* __restrict__ o0, void* __restrict__ o1, void* __restrict__ o2,
    const float* __restrict__ lng, const float* __restrict__ lnb,
    int ny, int nyz)
{
  constexpr int WC = COLS / 64;
  constexpr int PS = COLS * 64;
  constexpr int ROWB = COLS * 2;
  __shared__ __align__(16) char Bs[4 * PS];
  __shared__ float redbuf[(EPI == 3) ? 1280 : 4];
  const int bid = blockIdx.x;
  const int rest = bid >> 3;
  const int yz = rest % nyz;
  const int bx = ((rest / nyz) << 3) | (bid & 7);
  const int y = yz % ny;
  const int z = yz / ny;
  const ushort* Wt = (z == 0) ? Wt0 : ((z == 1) ? Wt1 : Wt2);
  const float* bias = (z == 0) ? b0 : ((z == 1) ? b1 : b2);
  void* outp = (z == 0) ? o0 : ((z == 1) ? o1 : o2);
  const int pcol = y * COLS;

  const int tid = threadIdx.x;
  const int wave = tid >> 6, lane = tid & 63;
  const int wc = wave % WC, wr = wave / WC;
  const int l15 = lane & 15, l4 = lane >> 4;
  const int row0 = bx * 128;
  const int sn = tid >> 1, sseg = tid & 1;

  f32x4 acc[4][4];
#pragma unroll
  for (int i = 0; i < 4; ++i)
#pragma unroll
    for (int j = 0; j < 4; ++j) acc[i][j] = (f32x4)0.f;

#pragma unroll
  for (int half = 0; half < 2; ++half) {
    if (half) __syncthreads();
    {
      const ushort* src = Wt + (size_t)(pcol + sn) * 256 + half * 128 + sseg * 64;
#pragma unroll
      for (int c = 0; c < 8; ++c) {
        uint4 w = *(const uint4*)(src + c * 8);
        int plane = sseg * 2 + (c >> 2);
        char* dst = Bs + plane * PS + sn * 64 + (((c & 3) * 16) ^ (((sn >> 1) & 3) << 4));
        *(uint4*)dst = w;
      }
    }
    __syncthreads();
#pragma unroll
    for (int ks = 0; ks < 4; ++ks) {
      short8 af[4];
#pragma unroll
      for (int mfa = 0; mfa < 4; ++mfa)
        af[mfa] = *(const short8*)(A + (size_t)(row0 + wr * 64 + mfa * 16 + l15) * 256 + half * 128 + ks * 32 + l4 * 8);
#pragma unroll
      for (int nfb = 0; nfb < 4; ++nfb) {
        int n = wc * 64 + nfb * 16 + l15;
        short8 bf = *(const short8*)(Bs + ks * PS + n * 64 + ((l4 * 16) ^ (((n >> 1) & 3) << 4)));
#pragma unroll
        for (int mfa = 0; mfa < 4; ++mfa)
          acc[mfa][nfb] = __builtin_amdgcn_mfma_f32_16x16x32_bf16(bf, af[mfa], acc[mfa][nfb], 0, 0, 0);
      }
    }
  }

  if constexpr (EPI == 0) {
    __syncthreads();
#pragma unroll
    for (int nfb = 0; nfb < 4; ++nfb) {
      f32x4 bv = *(const f32x4*)(bias + pcol + wc * 64 + nfb * 16 + l4 * 4);
      int colb = wc * 128 + nfb * 32 + l4 * 8;
#pragma unroll
      for (int mfa = 0; mfa < 4; ++mfa) {
        int row = wr * 64 + mfa * 16 + l15;
        ushort4v pk;
#pragma unroll
        for (int i = 0; i < 4; ++i) pk[i] = f2bf(acc[mfa][nfb][i] + bv[i]);
        *(ushort4v*)(Bs + row * ROWB + (colb ^ ((row & 7) << 4))) = pk;
      }
    }
    __syncthreads();
    const int srow = tid >> 2, seg = tid & 3;
#pragma unroll
    for (int rr = 0; rr < 2; ++rr) {
      int row = srow + rr * 64;
      int x = (row & 7) << 4;
      ushort* gdst = (ushort*)outp + (size_t)(row0 + row) * 256 + pcol;
#pragma unroll
      for (int it = 0; it < 4; ++it) {
        int colb = seg * 16 + it * 64;
        uint4 v = *(const uint4*)(Bs + row * ROWB + (colb ^ x));
        *(uint4*)(gdst + colb / 2) = v;
      }
    }
  } else {
    float* red1 = redbuf;
    float* red2 = redbuf + 512;
    float* mv_ = redbuf + 1024;
    float* rv_ = redbuf + 1152;
    float s1[4] = {0.f, 0.f, 0.f, 0.f}, s2[4] = {0.f, 0.f, 0.f, 0.f};
#pragma unroll
    for (int nfb = 0; nfb < 4; ++nfb) {
      int col0 = wc * 64 + nfb * 16 + l4 * 4;
      f32x4 bv = *(const f32x4*)(bias + col0);
#pragma unroll
      for (int mfa = 0; mfa < 4; ++mfa) {
        size_t row = (size_t)row0 + wr * 64 + mfa * 16 + l15;
        ushort4v rz = *(const ushort4v*)(A + row * 256 + col0);
#pragma unroll
        for (int i = 0; i < 4; ++i) {
          float zz = bf2f(rz[i]) + fmaxf(acc[mfa][nfb][i] + bv[i], 0.f);
          acc[mfa][nfb][i] = zz;
          s1[mfa] += zz;
          s2[mfa] += zz * zz;
        }
      }
    }
#pragma unroll
    for (int mfa = 0; mfa < 4; ++mfa) {
      s1[mfa] += __shfl_xor(s1[mfa], 16); s1[mfa] += __shfl_xor(s1[mfa], 32);
      s2[mfa] += __shfl_xor(s2[mfa], 16); s2[mfa] += __shfl_xor(s2[mfa], 32);
    }
    if (l4 == 0) {
#pragma unroll
      for (int mfa = 0; mfa < 4; ++mfa) {
        red1[wc * 128 + wr * 64 + mfa * 16 + l15] = s1[mfa];
        red2[wc * 128 + wr * 64 + mfa * 16 + l15] = s2[mfa];
      }
    }
    __syncthreads();
    if (tid < 128) {
      float m1 = red1[tid] + red1[128 + tid] + red1[256 + tid] + red1[384 + tid];
      float m2 = red2[tid] + red2[128 + tid] + red2[256 + tid] + red2[384 + tid];
      float mean = m1 * 0.00390625f;
      float var = m2 * 0.00390625f - mean * mean;
      mv_[tid] = mean;
      rv_[tid] = rsqrtf(var + 1e-5f);
    }
    __syncthreads();
#pragma unroll
    for (int nfb = 0; nfb < 4; ++nfb) {
      int col0 = wc * 64 + nfb * 16 + l4 * 4;
      f32x4 gg = *(const f32x4*)(lng + col0);
      f32x4 bb = *(const f32x4*)(lnb + col0);
      int colb = col0 * 2;
#pragma unroll
      for (int mfa = 0; mfa < 4; ++mfa) {
        int lr = wr * 64 + mfa * 16 + l15;
        float mean = mv_[lr], rs = rv_[lr];
        if constexpr (OUTF32) {
          f32x4 w;
#pragma unroll
          for (int i = 0; i < 4; ++i) w[i] = (acc[mfa][nfb][i] - mean) * rs * gg[i] + bb[i];
          *(f32x4*)((float*)outp + ((size_t)row0 + lr) * 256 + col0) = w;
        } else {
          ushort4v pk;
#pragma unroll
          for (int i = 0; i < 4; ++i) pk[i] = f2bf((acc[mfa][nfb][i] - mean) * rs * gg[i] + bb[i]);
          *(ushort4v*)(Bs + lr * ROWB + (colb ^ ((lr & 7) << 4))) = pk;
        }
      }
    }
    if constexpr (!OUTF32) {
      __syncthreads();
      const int srow = tid >> 2, seg = tid & 3;
      int x = (srow & 7) << 4;
      ushort* gdst = (ushort*)outp + (size_t)(row0 + srow) * 256;
#pragma unroll
      for (int it = 0; it < 8; ++it) {
        int colb = seg * 16 + it * 64;
        uint4 v = *(const uint4*)(Bs + srow * ROWB + (colb ^ x));
        *(uint4*)(gdst + colb / 2) = v;
      }
    }
  }
}

// ---------------- attn_big: nq small (64/32), nk=2048, masked, q shared across batch ----
template <int MF>
__global__ __launch_bounds__(512) void attn_big(
    const ushort* __restrict__ qb, const ushort* __restrict__ kb,
    const ushort* __restrict__ vb, const float* __restrict__ mask,
    ushort* __restrict__ O)
{
  __shared__ __align__(16) ushort Ps[8][64][72];
  __shared__ __align__(16) ushort Vt[8][32][72];
  const int h = blockIdx.x, b = blockIdx.y;
  const int tid = threadIdx.x;
  const int w = tid >> 6, lane = tid & 63;
  const int l15 = lane & 15, l4 = lane >> 4;
  const int koff = l4 * 8;
  const int kvbase = b * 2048;

  short8 qf[MF];
#pragma unroll
  for (int mf = 0; mf < MF; ++mf)
    qf[mf] = *(const short8*)(qb + (size_t)(mf * 16 + l15) * 256 + h * 32 + koff);

  f32x4 Oa[MF][2];
  float Mr[MF][4], Lr[MF][4];
#pragma unroll
  for (int mf = 0; mf < MF; ++mf) {
    Oa[mf][0] = (f32x4)0.f; Oa[mf][1] = (f32x4)0.f;
#pragma unroll
    for (int r = 0; r < 4; ++r) { Mr[mf][r] = -1e30f; Lr[mf][r] = 0.f; }
  }

  for (int c = 0; c < 4; ++c) {
    const int kc = w * 256 + c * 64;
    f32x4 S[MF][4];
#pragma unroll
    for (int nf = 0; nf < 4; ++nf) {
      short8 kf = *(const short8*)(kb + (size_t)(kvbase + kc + nf * 16 + l15) * 256 + h * 32 + koff);
#pragma unroll
      for (int mf = 0; mf < MF; ++mf)
        S[mf][nf] = __builtin_amdgcn_mfma_f32_16x16x32_bf16(qf[mf], kf, (f32x4)0.f, 0, 0, 0);
    }
    float mv[4];
#pragma unroll
    for (int nf = 0; nf < 4; ++nf)
      mv[nf] = mask[(size_t)b * 2048 + kc + nf * 16 + l15];
#pragma unroll
    for (int mf = 0; mf < MF; ++mf)
#pragma unroll
      for (int nf = 0; nf < 4; ++nf)
#pragma unroll
        for (int r = 0; r < 4; ++r) {
          float s = S[mf][nf][r] * 0.0625f;
          S[mf][nf][r] = (mv[nf] != 0.f) ? s : -1e4f;
        }
#pragma unroll
    for (int mf = 0; mf < MF; ++mf)
#pragma unroll
      for (int r = 0; r < 4; ++r) {
        float pm = fmaxf(fmaxf(S[mf][0][r], S[mf][1][r]), fmaxf(S[mf][2][r], S[mf][3][r]));
        pm = fmaxf(pm, __shfl_xor(pm, 1));
        pm = fmaxf(pm, __shfl_xor(pm, 2));
        pm = fmaxf(pm, __shfl_xor(pm, 4));
        pm = fmaxf(pm, __shfl_xor(pm, 8));
        float Mnew = fmaxf(Mr[mf][r], pm);
        float corr = __expf(Mr[mf][r] - Mnew);
        Mr[mf][r] = Mnew;
        float rs = 0.f;
#pragma unroll
        for (int nf = 0; nf < 4; ++nf) {
          float p = __expf(S[mf][nf][r] - Mnew);
          S[mf][nf][r] = p;
          rs += p;
        }
        rs += __shfl_xor(rs, 1);
        rs += __shfl_xor(rs, 2);
        rs += __shfl_xor(rs, 4);
        rs += __shfl_xor(rs, 8);
        Lr[mf][r] = Lr[mf][r] * corr + rs;
        Oa[mf][0][r] *= corr;
        Oa[mf][1][r] *= corr;
      }
#pragma unroll
    for (int dblk = 0; dblk < 4; ++dblk) {
      short8 vv = *(const short8*)(vb + (size_t)(kvbase + kc + lane) * 256 + h * 32 + dblk * 8);
#pragma unroll
      for (int j = 0; j < 8; ++j) Vt[w][dblk * 8 + j][lane] = (ushort)vv[j];
    }
#pragma unroll
    for (int mf = 0; mf < MF; ++mf)
#pragma unroll
      for (int nf = 0; nf < 4; ++nf)
#pragma unroll
        for (int r = 0; r < 4; ++r)
          Ps[w][mf * 16 + l4 * 4 + r][nf * 16 + l15] = f2bf(S[mf][nf][r]);
#pragma unroll
    for (int ks = 0; ks < 2; ++ks) {
      short8 pf[MF];
#pragma unroll
      for (int mf = 0; mf < MF; ++mf)
        pf[mf] = *(const short8*)&Ps[w][mf * 16 + l15][ks * 32 + koff];
#pragma unroll
      for (int nf2 = 0; nf2 < 2; ++nf2) {
        short8 vf = *(const short8*)&Vt[w][nf2 * 16 + l15][ks * 32 + koff];
#pragma unroll
        for (int mf = 0; mf < MF; ++mf)
          Oa[mf][nf2] = __builtin_amdgcn_mfma_f32_16x16x32_bf16(pf[mf], vf, Oa[mf][nf2], 0, 0, 0);
      }
    }
  }

  __syncthreads();
  float* Mw = (float*)&Ps[0][0][0];
  float* Lw = Mw + 512;
  float* Ow = Lw + 512;  // [8][64][33]
#pragma unroll
  for (int mf = 0; mf < MF; ++mf)
#pragma unroll
    for (int r = 0; r < 4; ++r) {
      int row = mf * 16 + l4 * 4 + r;
      if (l15 == 0) { Mw[w * 64 + row] = Mr[mf][r]; Lw[w * 64 + row] = Lr[mf][r]; }
#pragma unroll
      for (int nf2 = 0; nf2 < 2; ++nf2)
        Ow[(w * 64 + row) * 33 + nf2 * 16 + l15] = Oa[mf][nf2][r];
    }
  __syncthreads();
  const int NQ = MF * 16;
  int row = tid >> 3, dg = tid & 7;
  if (row < NQ) {
    float mm = -1e30f;
#pragma unroll
    for (int s = 0; s < 8; ++s) mm = fmaxf(mm, Mw[s * 64 + row]);
    float den = 0.f, es[8];
#pragma unroll
    for (int s = 0; s < 8; ++s) {
      es[s] = __expf(Mw[s * 64 + row] - mm);
      den += Lw[s * 64 + row] * es[s];
    }
    float invden = 1.f / den;
    ushort4v pk;
#pragma unroll
    for (int i = 0; i < 4; ++i) {
      int d = dg * 4 + i;
      float num = 0.f;
#pragma unroll
      for (int s = 0; s < 8; ++s) num += Ow[(s * 64 + row) * 33 + d] * es[s];
      float qv = bf2f(qb[(size_t)row * 256 + h * 32 + d]);
      pk[i] = f2bf(qv + num * invden);
    }
    *(ushort4v*)(O + (size_t)(b * NQ + row) * 256 + h * 32 + dg * 4) = pk;
  }
}

// ---------------- mab1_fused: q-proj + attention(nk=64) + LN0 + Wo + LN1 ----------------
// grid(qt=32, b=32), block 512 = 8 waves = 8 heads over the same 64 q-rows.
// Deep prefetch: Vt staging, K frags, and full Wo B-fragment set loaded at entry.
__global__ __launch_bounds__(512, 1) void mab1_fused(
    const ushort* __restrict__ xb, const ushort* __restrict__ wq,
    const float* __restrict__ bq,
    const ushort* __restrict__ kb, const ushort* __restrict__ vb,
    const ushort* __restrict__ wo, const float* __restrict__ bo,
    const float* __restrict__ g0, const float* __restrict__ b0v,
    const float* __restrict__ g1, const float* __restrict__ b1v,
    ushort* __restrict__ outb)
{
  __shared__ __align__(16) ushort Qs[8][64][40];   // 40KB: q tiles, wave-private
  __shared__ __align__(16) ushort Ps[8][64][72];   // 72KB: P tiles; later o_s[64][264]
  __shared__ __align__(16) ushort Vt[8][32][72];   // 36KB: V^T tiles
  __shared__ float red1[8][64], red2[8][64], mv_[64], rv_[64];
  ushort* o_s = &Ps[0][0][0];
  constexpr int OS = 264;

  const int qt = blockIdx.x, b = blockIdx.y;
  const int tid = threadIdx.x;
  const int w = tid >> 6, lane = tid & 63;  // w = head / col-group
  const int l15 = lane & 15, l4 = lane >> 4;
  const int koff = l4 * 8;
  const size_t row0 = (size_t)b * 2048 + qt * 64;
  const int kvbase = b * 64;
  const int h = w;

  // ---- phase 0: deep prefetch (addresses known at entry) ----
  // V -> Vt staging (wave-private LDS, no barrier needed before PV)
#pragma unroll
  for (int dblk = 0; dblk < 4; ++dblk) {
    short8 vv = *(const short8*)(vb + (size_t)(kvbase + lane) * 256 + h * 32 + dblk * 8);
#pragma unroll
    for (int j = 0; j < 8; ++j) Vt[w][dblk * 8 + j][lane] = (ushort)vv[j];
  }
  // K fragments
  short8 kf[4];
#pragma unroll
  for (int nf = 0; nf < 4; ++nf)
    kf[nf] = *(const short8*)(kb + (size_t)(kvbase + nf * 16 + l15) * 256 + h * 32 + koff);
  // full Wo B-fragment panel for this wave's 32 output cols
  short8 wof[2][8];
#pragma unroll
  for (int nfb = 0; nfb < 2; ++nfb) {
    int n = w * 32 + nfb * 16 + l15;
#pragma unroll
    for (int ks = 0; ks < 8; ++ks)
      wof[nfb][ks] = *(const short8*)(wo + (size_t)n * 256 + ks * 32 + koff);
  }

  // ---- phase 1: q[64][32] (head w) = xb[rows] @ Wq[:, w*32..] + bq -> Qs (bf16) ----
  {
    f32x4 qa[4][2];
#pragma unroll
    for (int i = 0; i < 4; ++i) { qa[i][0] = (f32x4)0.f; qa[i][1] = (f32x4)0.f; }
#pragma unroll
    for (int ks = 0; ks < 8; ++ks) {
      short8 af[4];
#pragma unroll
      for (int mfa = 0; mfa < 4; ++mfa)
        af[mfa] = *(const short8*)(xb + (row0 + mfa * 16 + l15) * 256 + ks * 32 + koff);
#pragma unroll
      for (int nfb = 0; nfb < 2; ++nfb) {
        int n = w * 32 + nfb * 16 + l15;
        short8 bf = *(const short8*)(wq + (size_t)n * 256 + ks * 32 + koff);
#pragma unroll
        for (int mfa = 0; mfa < 4; ++mfa)  // swapped: D row<-l15(A row), col<-l4*4+i (n)
          qa[mfa][nfb] = __builtin_amdgcn_mfma_f32_16x16x32_bf16(bf, af[mfa], qa[mfa][nfb], 0, 0, 0);
      }
    }
#pragma unroll
    for (int nfb = 0; nfb < 2; ++nfb) {
      f32x4 bv = *(const f32x4*)(bq + w * 32 + nfb * 16 + l4 * 4);
#pragma unroll
      for (int mfa = 0; mfa < 4; ++mfa) {
        ushort4v pk;
#pragma unroll
        for (int i = 0; i < 4; ++i) pk[i] = f2bf(qa[mfa][nfb][i] + bv[i]);
        *(ushort4v*)&Qs[w][mfa * 16 + l15][nfb * 16 + l4 * 4] = pk;
      }
    }
  }

  // ---- phase 2: attention (q from Qs, K from preloaded frags) ----
  short8 qf[4];
#pragma unroll
  for (int mf = 0; mf < 4; ++mf)
    qf[mf] = *(const short8*)&Qs[w][mf * 16 + l15][koff];

  f32x4 S[4][4];
#pragma unroll
  for (int nf = 0; nf < 4; ++nf) {
#pragma unroll
    for (int mf = 0; mf < 4; ++mf)
      S[mf][nf] = __builtin_amdgcn_mfma_f32_16x16x32_bf16(qf[mf], kf[nf], (f32x4)0.f, 0, 0, 0);
  }
  float Lr[4][4];
#pragma unroll
  for (int mf = 0; mf < 4; ++mf)
#pragma unroll
    for (int r = 0; r < 4; ++r) {
      float pm = fmaxf(fmaxf(S[mf][0][r], S[mf][1][r]), fmaxf(S[mf][2][r], S[mf][3][r])) * 0.0625f;
      pm = fmaxf(pm, __shfl_xor(pm, 1));
      pm = fmaxf(pm, __shfl_xor(pm, 2));
      pm = fmaxf(pm, __shfl_xor(pm, 4));
      pm = fmaxf(pm, __shfl_xor(pm, 8));
      float rs = 0.f;
#pragma unroll
      for (int nf = 0; nf < 4; ++nf) {
        float p = __expf(S[mf][nf][r] * 0.0625f - pm);
        S[mf][nf][r] = p;
        rs += p;
      }
      rs += __shfl_xor(rs, 1);
      rs += __shfl_xor(rs, 2);
      rs += __shfl_xor(rs, 4);
      rs += __shfl_xor(rs, 8);
      Lr[mf][r] = rs;
    }
#pragma unroll
  for (int mf = 0; mf < 4; ++mf)
#pragma unroll
    for (int nf = 0; nf < 4; ++nf)
#pragma unroll
      for (int r = 0; r < 4; ++r)
        Ps[w][mf * 16 + l4 * 4 + r][nf * 16 + l15] = f2bf(S[mf][nf][r]);
  f32x4 Oa[4][2];
#pragma unroll
  for (int mf = 0; mf < 4; ++mf) { Oa[mf][0] = (f32x4)0.f; Oa[mf][1] = (f32x4)0.f; }
#pragma unroll
  for (int ks = 0; ks < 2; ++ks) {
    short8 pf[4];
#pragma unroll
    for (int mf = 0; mf < 4; ++mf)
      pf[mf] = *(const short8*)&Ps[w][mf * 16 + l15][ks * 32 + koff];
#pragma unroll
    for (int nf2 = 0; nf2 < 2; ++nf2) {
      short8 vf = *(const short8*)&Vt[w][nf2 * 16 + l15][ks * 32 + koff];
#pragma unroll
      for (int mf = 0; mf < 4; ++mf)
        Oa[mf][nf2] = __builtin_amdgcn_mfma_f32_16x16x32_bf16(pf[mf], vf, Oa[mf][nf2], 0, 0, 0);
    }
  }

  // ---- phase 3: o = q + PV/L; LN0 stats ----
  {
    float s1[4][4], s2[4][4];
#pragma unroll
    for (int mf = 0; mf < 4; ++mf)
#pragma unroll
      for (int r = 0; r < 4; ++r) {
        float invL = 1.f / Lr[mf][r];
        s1[mf][r] = 0.f; s2[mf][r] = 0.f;
#pragma unroll
        for (int nf2 = 0; nf2 < 2; ++nf2) {
          float qv = bf2f(Qs[w][mf * 16 + l4 * 4 + r][nf2 * 16 + l15]);
          float z = qv + Oa[mf][nf2][r] * invL;
          Oa[mf][nf2][r] = z;
          s1[mf][r] += z;
          s2[mf][r] += z * z;
        }
#pragma unroll
        for (int off = 1; off < 16; off <<= 1) {
          s1[mf][r] += __shfl_xor(s1[mf][r], off);
          s2[mf][r] += __shfl_xor(s2[mf][r], off);
        }
        if (l15 == 0) {
          int row = mf * 16 + l4 * 4 + r;
          red1[w][row] = s1[mf][r];
          red2[w][row] = s2[mf][r];
        }
      }
  }
  __syncthreads();  // all waves past PV (Ps/Vt dead); red1/red2 complete
  if (tid < 64) {
    float m1 = 0.f, m2 = 0.f;
#pragma unroll
    for (int s = 0; s < 8; ++s) { m1 += red1[s][tid]; m2 += red2[s][tid]; }
    float mean = m1 * 0.00390625f;
    float var = m2 * 0.00390625f - mean * mean;
    mv_[tid] = mean;
    rv_[tid] = rsqrtf(var + 1e-5f);
  }
  __syncthreads();
  // apply LN0 -> o_s (overlay on Ps)
#pragma unroll
  for (int nf2 = 0; nf2 < 2; ++nf2) {
    int col = h * 32 + nf2 * 16 + l15;
    float gc = g0[col], bc = b0v[col];
#pragma unroll
    for (int mf = 0; mf < 4; ++mf)
#pragma unroll
      for (int r = 0; r < 4; ++r) {
        int row = mf * 16 + l4 * 4 + r;
        float v = (Oa[mf][nf2][r] - mv_[row]) * rv_[row] * gc + bc;
        o_s[row * OS + col] = f2bf(v);
      }
  }
  __syncthreads();

  // ---- phase 4: Wo GEMM (cols w*32..) + resid + LN1, B-frags preloaded ----
  f32x4 oa[4][2];
#pragma unroll
  for (int i = 0; i < 4; ++i) { oa[i][0] = (f32x4)0.f; oa[i][1] = (f32x4)0.f; }
#pragma unroll
  for (int ks = 0; ks < 8; ++ks) {
    short8 af[4];
#pragma unroll
    for (int mfa = 0; mfa < 4; ++mfa)
      af[mfa] = *(const short8*)&o_s[(mfa * 16 + l15) * OS + ks * 32 + koff];
#pragma unroll
    for (int nfb = 0; nfb < 2; ++nfb) {
#pragma unroll
      for (int mfa = 0; mfa < 4; ++mfa)
        oa[mfa][nfb] = __builtin_amdgcn_mfma_f32_16x16x32_bf16(wof[nfb][ks], af[mfa], oa[mfa][nfb], 0, 0, 0);
    }
  }
  float t1[4] = {0.f, 0.f, 0.f, 0.f}, t2[4] = {0.f, 0.f, 0.f, 0.f};
#pragma unroll
  for (int nfb = 0; nfb < 2; ++nfb) {
    int col0 = w * 32 + nfb * 16 + l4 * 4;
    f32x4 bv = *(const f32x4*)(bo + col0);
#pragma unroll
    for (int mfa = 0; mfa < 4; ++mfa) {
      int row = mfa * 16 + l15;
      ushort4v rz = *(const ushort4v*)&o_s[row * OS + col0];
#pragma unroll
      for (int i = 0; i < 4; ++i) {
        float zz = bf2f(rz[i]) + fmaxf(oa[mfa][nfb][i] + bv[i], 0.f);
        oa[mfa][nfb][i] = zz;
        t1[mfa] += zz;
        t2[mfa] += zz * zz;
      }
    }
  }
#pragma unroll
  for (int mfa = 0; mfa < 4; ++mfa) {
    t1[mfa] += __shfl_xor(t1[mfa], 16); t1[mfa] += __shfl_xor(t1[mfa], 32);
    t2[mfa] += __shfl_xor(t2[mfa], 16); t2[mfa] += __shfl_xor(t2[mfa], 32);
  }
  if (l4 == 0) {
#pragma unroll
    for (int mfa = 0; mfa < 4; ++mfa) {
      red1[w][mfa * 16 + l15] = t1[mfa];
      red2[w][mfa * 16 + l15] = t2[mfa];
    }
  }
  __syncthreads();
  if (tid < 64) {
    float m1 = 0.f, m2 = 0.f;
#pragma unroll
    for (int s = 0; s < 8; ++s) { m1 += red1[s][tid]; m2 += red2[s][tid]; }
    float mean = m1 * 0.00390625f;
    float var = m2 * 0.00390625f - mean * mean;
    mv_[tid] = mean;
    rv_[tid] = rsqrtf(var + 1e-5f);
  }
  __syncthreads();
#pragma unroll
  for (int nfb = 0; nfb < 2; ++nfb) {
    int col0 = w * 32 + nfb * 16 + l4 * 4;
    f32x4 gg = *(const f32x4*)(g1 + col0);
    f32x4 bb = *(const f32x4*)(b1v + col0);
#pragma unroll
    for (int mfa = 0; mfa < 4; ++mfa) {
      int row = mfa * 16 + l15;
      ushort4v pk;
#pragma unroll
      for (int i = 0; i < 4; ++i)
        pk[i] = f2bf((oa[mfa][nfb][i] - mv_[row]) * rv_[row] * gg[i] + bb[i]);
      *(ushort4v*)&o_s[row * OS + col0] = pk;  // per-lane same addr as resid read: safe
    }
  }
  __syncthreads();
  // cooperative full-line store: 512 thr -> 64 rows x 8 segs of 64B
  {
    const int r_ = tid >> 3, sg = tid & 7;
    ushort* gdst = outb + (row0 + r_) * 256 + sg * 32;
    const ushort* src = &o_s[r_ * OS + sg * 32];
#pragma unroll
    for (int it = 0; it < 4; ++it) {
      uint4 v = *(const uint4*)(src + it * 8);
      *(uint4*)(gdst + it * 8) = v;
    }
  }
}

// ---------------- small LayerNorm: bf16 in/out, wave per row ----------------
__global__ __launch_bounds__(256) void ln4(
    const ushort* __restrict__ in, ushort* __restrict__ out,
    const float* __restrict__ g, const float* __restrict__ bb)
{
  const int w = threadIdx.x >> 6, lane = threadIdx.x & 63;
  const size_t row = (size_t)blockIdx.x * 4 + w;
  ushort4v u = *(const ushort4v*)(in + row * 256 + lane * 4);
  float v[4];
#pragma unroll
  for (int i = 0; i < 4; ++i) v[i] = bf2f(u[i]);
  float s1 = v[0] + v[1] + v[2] + v[3];
  float s2 = v[0] * v[0] + v[1] * v[1] + v[2] * v[2] + v[3] * v[3];
#pragma unroll
  for (int off = 1; off < 64; off <<= 1) {
    s1 += __shfl_xor(s1, off);
    s2 += __shfl_xor(s2, off);
  }
  float mean = s1 * 0.00390625f;
  float var = s2 * 0.00390625f - mean * mean;
  float rs = rsqrtf(var + 1e-5f);
  f32x4 gg = *(const f32x4*)(g + lane * 4);
  f32x4 bv = *(const f32x4*)(bb + lane * 4);
  ushort4v p;
#pragma unroll
  for (int i = 0; i < 4; ++i) p[i] = f2bf((v[i] - mean) * rs * gg[i] + bv[i]);
  *(ushort4v*)(out + row * 256 + lane * 4) = p;
}

extern "C" void kernel_launch(void* const* d_in, const int* in_sizes, int n_in,
                              void* d_out, int out_size, void* d_ws, size_t ws_size,
                              hipStream_t stream) {
  const float* xv = (const float*)d_in[0];
  const float* yt = (const float*)d_in[1];
  const float* pmask = (const float*)d_in[2];
  const float* prW = (const float*)d_in[3];
  const float* prb = (const float*)d_in[4];
  const float* iI = (const float*)d_in[5];
  const float* iWq = (const float*)d_in[6];
  const float* ibq = (const float*)d_in[7];
  const float* iWk = (const float*)d_in[8];
  const float* ibk = (const float*)d_in[9];
  const float* iWv = (const float*)d_in[10];
  const float* ibv = (const float*)d_in[11];
  const float* iWo = (const float*)d_in[12];
  const float* ibo = (const float*)d_in[13];
  const float* ig0 = (const float*)d_in[14];
  const float* ib0 = (const float*)d_in[15];
  const float* ig1 = (const float*)d_in[16];
  const float* ib1 = (const float*)d_in[17];
  const float* pS = (const float*)d_in[18];
  const float* pWq = (const float*)d_in[19];
  const float* pbq = (const float*)d_in[20];
  const float* pWk = (const float*)d_in[21];
  const float* pbk = (const float*)d_in[22];
  const float* pWv = (const float*)d_in[23];
  const float* pbv = (const float*)d_in[24];
  const float* pWo = (const float*)d_in[25];
  const float* pbo = (const float*)d_in[26];
  const float* pg0 = (const float*)d_in[27];
  const float* pb0 = (const float*)d_in[28];
  const float* pg1 = (const float*)d_in[29];
  const float* pb1 = (const float*)d_in[30];

  char* ws = (char*)d_ws;
  if (ws_size < 172621824u) return;
  ushort* xb = (ushort*)(ws + 0);              // 32MB (B*N x 256)
  ushort* ob = (ushort*)(ws + 33554432);       // 32MB (attn/LN scratch)
  ushort* hb = (ushort*)(ws + 67108864);       // 1MB  (B*NI x 256)
  ushort* kbw = (ushort*)(ws + 101711872);     // 32MB
  ushort* vbw = (ushort*)(ws + 135266304);     // 32MB
  ushort* wt = (ushort*)(ws + 168820736);      // 3.5MB transposed weights
  ushort* q_all = (ushort*)(ws + 172490752);   // 112KB tiny-q outputs

  prep_weights<<<dim3(16, 28), 256, 0, stream>>>(iWq, iWk, iWv, iWo, pWq, pWk, pWv, pWo, wt);
  proj_gelu<<<8192, 256, 0, stream>>>(xv, yt, prW, prb, xb);
  gemm_q<<<4, 256, 0, stream>>>(iI, pS, wt, ibq, pbq, q_all);

  for (int l = 0; l < 3; ++l) {
    const int s0 = l * 2, s1 = l * 2 + 1;
    const ushort* wk = wt + (size_t)(l * 8 + 1) * 65536;
    const ushort* wv = wt + (size_t)(l * 8 + 2) * 65536;
    const ushort* wo0 = wt + (size_t)(l * 8 + 3) * 65536;
    const ushort* wq1 = wt + (size_t)(l * 8 + 4) * 65536;
    const ushort* wk1 = wt + (size_t)(l * 8 + 5) * 65536;
    const ushort* wv1 = wt + (size_t)(l * 8 + 6) * 65536;
    const ushort* wo1 = wt + (size_t)(l * 8 + 7) * 65536;
    // ---- mab0 K,V (consume xb): batched, A-sharers colocated on one XCD ----
    gemm_bp<0, false, 128><<<2048, 256, 0, stream>>>(
        xb, wk, wv, wv, ibk + s0 * 256, ibv + s0 * 256, ibv + s0 * 256,
        kbw, vbw, vbw, nullptr, nullptr, 2, 4);
    attn_big<4><<<dim3(8, 32), 512, 0, stream>>>(q_all + l * 16384, kbw, vbw, pmask, ob);
    ln4<<<512, 256, 0, stream>>>(ob, ob, ig0 + s0 * 256, ib0 + s0 * 256);
    gemm_bp<3, false, 256><<<16, 512, 0, stream>>>(
        ob, wo0, wo0, wo0, ibo + s0 * 256, ibo + s0 * 256, ibo + s0 * 256,
        hb, hb, hb, ig1 + s0 * 256, ib1 + s0 * 256, 1, 1);
    // ---- mab1 K,V (consume hb) ----
    gemm_bp<0, false, 128><<<64, 256, 0, stream>>>(
        hb, wk1, wv1, wv1, ibk + s1 * 256, ibv + s1 * 256, ibv + s1 * 256,
        kbw, vbw, vbw, nullptr, nullptr, 2, 4);
    // ---- mab1 fused: q-proj + attention + LN0 + Wo + LN1, xb in-place ----
    mab1_fused<<<dim3(32, 32), 512, 0, stream>>>(
        xb, wq1, ibq + s1 * 256, kbw, vbw, wo1, ibo + s1 * 256,
        ig0 + s1 * 256, ib0 + s1 * 256, ig1 + s1 * 256, ib1 + s1 * 256, xb);
  }
  // ---- PMA: S attends to x ----
  gemm_bp<0, false, 128><<<2048, 256, 0, stream>>>(
      xb, wt + (size_t)25 * 65536, wt + (size_t)26 * 65536, wt + (size_t)26 * 65536,
      pbk, pbv, pbv, kbw, vbw, vbw, nullptr, nullptr, 2, 4);
  attn_big<2><<<dim3(8, 32), 512, 0, stream>>>(q_all + 49152, kbw, vbw, pmask, ob);
  ln4<<<256, 256, 0, stream>>>(ob, ob, pg0, pb0);
  gemm_bp<3, true, 256><<<8, 512, 0, stream>>>(
      ob, wt + (size_t)27 * 65536, wt + (size_t)27 * 65536, wt + (size_t)27 * 65536,
      pbo, pbo, pbo, d_out, d_out, d_out, pg1, pb1, 1, 1);
}

// Round 10
// 799.455 us; speedup vs baseline: 1.1861x; 1.0670x over previous
//
#include <hip/hip_runtime.h>
#include <hip/hip_bf16.h>

// SetTransformer encoder forward. B=32,N=2048,D=256,H=8,dh=32,NI=64,NL=3,NS=32.
// Round 10: mab1_fused LDS diet 152.5KB -> 74.5KB (per-mf P staging, V^T half
// double-buffer, o_s overlays Qs) -> 2 blocks/CU, 2 dispatch rounds instead of 4.

typedef __attribute__((ext_vector_type(8))) short short8;
typedef __attribute__((ext_vector_type(4))) float f32x4;
typedef __attribute__((ext_vector_type(4))) ushort ushort4v;

__device__ __forceinline__ ushort f2bf(float f) {
  uint u = __builtin_bit_cast(uint, f);
  u += 0x7fffu + ((u >> 16) & 1u);
  return (ushort)(u >> 16);
}
__device__ __forceinline__ float bf2f(ushort h) {
  uint u = (uint)h << 16;
  return __builtin_bit_cast(float, u);
}

// ---------------- weight prep: transpose 256x256 f32 [k][n] -> bf16 [n][k] ----------------
__global__ __launch_bounds__(256) void prep_weights(
    const float* __restrict__ Wq, const float* __restrict__ Wk,
    const float* __restrict__ Wv, const float* __restrict__ Wo,
    const float* __restrict__ pWq, const float* __restrict__ pWk,
    const float* __restrict__ pWv, const float* __restrict__ pWo,
    ushort* __restrict__ wt)
{
  __shared__ float tile[64][65];
  const int m = blockIdx.y;          // 0..27
  const int t = blockIdx.x;          // 0..15
  const int tr = (t >> 2) * 64;      // k block
  const int tc = (t & 3) * 64;       // n block
  const float* src;
  if (m < 24) {
    int l = m >> 3, s = (m >> 2) & 1, w = m & 3;
    const float* base = (w == 0) ? Wq : (w == 1) ? Wk : (w == 2) ? Wv : Wo;
    src = base + (size_t)(l * 2 + s) * 65536;
  } else {
    int w = m & 3;
    src = (w == 0) ? pWq : (w == 1) ? pWk : (w == 2) ? pWv : pWo;
  }
  const int tid = threadIdx.x;
  const int cn = tid & 63;
  const int rk = tid >> 6;
#pragma unroll
  for (int j = 0; j < 16; ++j) {
    int kl = rk + j * 4;
    tile[kl][cn] = src[(size_t)(tr + kl) * 256 + tc + cn];
  }
  __syncthreads();
  ushort* dst = wt + (size_t)m * 65536;
#pragma unroll
  for (int j = 0; j < 16; ++j) {
    int nl = rk + j * 4;
    dst[(size_t)(tc + nl) * 256 + tr + cn] = f2bf(tile[cn][nl]);
  }
}

// ---------------- input projection + exact gelu -> bf16, 8 rows/block ----------------
__global__ __launch_bounds__(256) void proj_gelu(
    const float* __restrict__ xv, const float* __restrict__ yt,
    const float* __restrict__ pW, const float* __restrict__ pb,
    ushort* __restrict__ xb)
{
  const int d = threadIdx.x;
  const int row0 = blockIdx.x * 8;
  const float w0 = pW[d], w1 = pW[256 + d], w2 = pW[512 + d], w3 = pW[768 + d];
  const float bz = pb[d];
#pragma unroll
  for (int rr = 0; rr < 8; ++rr) {
    int row = row0 + rr;
    float f0 = xv[(size_t)row * 3 + 0];
    float f1 = xv[(size_t)row * 3 + 1];
    float f2 = xv[(size_t)row * 3 + 2];
    float f3 = yt[row];
    float a = bz + f0 * w0 + f1 * w1 + f2 * w2 + f3 * w3;
    float g = 0.5f * a * (1.f + erff(a * 0.70710678118654752f));
    xb[(size_t)row * 256 + d] = f2bf(g);
  }
}

// ---------------- batched tiny q-projections (f32 A, M=64/32) ----------------
__global__ __launch_bounds__(256) void gemm_q(
    const float* __restrict__ iI, const float* __restrict__ pS,
    const ushort* __restrict__ wt, const float* __restrict__ ibq,
    const float* __restrict__ pbq, ushort* __restrict__ q_all)
{
  const int bq = blockIdx.x;
  const float* A; const ushort* Wt; const float* bias; ushort* out; int M;
  if (bq < 3) { A = iI + bq * 16384; Wt = wt + (size_t)(bq * 8) * 65536; bias = ibq + bq * 512; out = q_all + bq * 16384; M = 64; }
  else        { A = pS; Wt = wt + (size_t)24 * 65536; bias = pbq; out = q_all + 49152; M = 32; }
  const int tid = threadIdx.x;
  const int wave = tid >> 6, lane = tid & 63;
  const int l15 = lane & 15, l4 = lane >> 4, koff = l4 * 8;
  f32x4 acc[4][4];
#pragma unroll
  for (int i = 0; i < 4; ++i)
#pragma unroll
    for (int j = 0; j < 4; ++j) acc[i][j] = (f32x4)0.f;
#pragma unroll
  for (int ks = 0; ks < 8; ++ks) {
    short8 af[4];
#pragma unroll
    for (int mf = 0; mf < 4; ++mf) {
      if (mf * 16 < M) {
        const float* ap = A + (size_t)(mf * 16 + l15) * 256 + ks * 32 + koff;
        float4 f0 = *(const float4*)ap;
        float4 f1 = *(const float4*)(ap + 4);
        short8 sv;
        sv[0] = (short)f2bf(f0.x); sv[1] = (short)f2bf(f0.y);
        sv[2] = (short)f2bf(f0.z); sv[3] = (short)f2bf(f0.w);
        sv[4] = (short)f2bf(f1.x); sv[5] = (short)f2bf(f1.y);
        sv[6] = (short)f2bf(f1.z); sv[7] = (short)f2bf(f1.w);
        af[mf] = sv;
      } else af[mf] = (short8)0;
    }
#pragma unroll
    for (int nf = 0; nf < 4; ++nf) {
      short8 bf = *(const short8*)(Wt + (size_t)(wave * 64 + nf * 16 + l15) * 256 + ks * 32 + koff);
#pragma unroll
      for (int mf = 0; mf < 4; ++mf)
        acc[mf][nf] = __builtin_amdgcn_mfma_f32_16x16x32_bf16(af[mf], bf, acc[mf][nf], 0, 0, 0);
    }
  }
#pragma unroll
  for (int mf = 0; mf < 4; ++mf) {
    if (mf * 16 >= M) continue;
#pragma unroll
    for (int nf = 0; nf < 4; ++nf) {
      int col = wave * 64 + nf * 16 + l15;
      float bcol = bias[col];
#pragma unroll
      for (int r = 0; r < 4; ++r)
        out[(size_t)(mf * 16 + l4 * 4 + r) * 256 + col] = f2bf(acc[mf][nf][r] + bcol);
    }
  }
}

// ---------------- B-panel GEMM: out = epi(A @ W + bias) ----------------
// 1-D grid with XCD-colocating decode: bid = (x&7) + 8*(yz + nyz*(x>>3)).
template <int EPI, bool OUTF32, int COLS>
__global__ __launch_bounds__(COLS * 2, (COLS == 128) ? 4 : 2) void gemm_bp(
    const ushort* __restrict__ A,
    const ushort* __restrict__ Wt0, const ushort* __restrict__ Wt1, const ushort* __restrict__ Wt2,
    const float* __restrict__ b0, const float* __restrict__ b1, const float* __restrict__ b2,
    void* __restrict__ o0, void* __restrict__ o1, void* __restrict__ o2,
    const float* __restrict__ lng, const float* __restrict__ lnb,
    int ny, int nyz)
{
  constexpr int WC = COLS / 64;
  constexpr int PS = COLS * 64;
  constexpr int ROWB = COLS * 2;
  __shared__ __align__(16) char Bs[4 * PS];
  __shared__ float redbuf[(EPI == 3) ? 1280 : 4];
  const int bid = blockIdx.x;
  const int rest = bid >> 3;
  const int yz = rest % nyz;
  const int bx = ((rest / nyz) << 3) | (bid & 7);
  const int y = yz % ny;
  const int z = yz / ny;
  const ushort* Wt = (z == 0) ? Wt0 : ((z == 1) ? Wt1 : Wt2);
  const float* bias = (z == 0) ? b0 : ((z == 1) ? b1 : b2);
  void* outp = (z == 0) ? o0 : ((z == 1) ? o1 : o2);
  const int pcol = y * COLS;

  const int tid = threadIdx.x;
  const int wave = tid >> 6, lane = tid & 63;
  const int wc = wave % WC, wr = wave / WC;
  const int l15 = lane & 15, l4 = lane >> 4;
  const int row0 = bx * 128;
  const int sn = tid >> 1, sseg = tid & 1;

  f32x4 acc[4][4];
#pragma unroll
  for (int i = 0; i < 4; ++i)
#pragma unroll
    for (int j = 0; j < 4; ++j) acc[i][j] = (f32x4)0.f;

#pragma unroll
  for (int half = 0; half < 2; ++half) {
    if (half) __syncthreads();
    {
      const ushort* src = Wt + (size_t)(pcol + sn) * 256 + half * 128 + sseg * 64;
#pragma unroll
      for (int c = 0; c < 8; ++c) {
        uint4 w = *(const uint4*)(src + c * 8);
        int plane = sseg * 2 + (c >> 2);
        char* dst = Bs + plane * PS + sn * 64 + (((c & 3) * 16) ^ (((sn >> 1) & 3) << 4));
        *(uint4*)dst = w;
      }
    }
    __syncthreads();
#pragma unroll
    for (int ks = 0; ks < 4; ++ks) {
      short8 af[4];
#pragma unroll
      for (int mfa = 0; mfa < 4; ++mfa)
        af[mfa] = *(const short8*)(A + (size_t)(row0 + wr * 64 + mfa * 16 + l15) * 256 + half * 128 + ks * 32 + l4 * 8);
#pragma unroll
      for (int nfb = 0; nfb < 4; ++nfb) {
        int n = wc * 64 + nfb * 16 + l15;
        short8 bf = *(const short8*)(Bs + ks * PS + n * 64 + ((l4 * 16) ^ (((n >> 1) & 3) << 4)));
#pragma unroll
        for (int mfa = 0; mfa < 4; ++mfa)
          acc[mfa][nfb] = __builtin_amdgcn_mfma_f32_16x16x32_bf16(bf, af[mfa], acc[mfa][nfb], 0, 0, 0);
      }
    }
  }

  if constexpr (EPI == 0) {
    __syncthreads();
#pragma unroll
    for (int nfb = 0; nfb < 4; ++nfb) {
      f32x4 bv = *(const f32x4*)(bias + pcol + wc * 64 + nfb * 16 + l4 * 4);
      int colb = wc * 128 + nfb * 32 + l4 * 8;
#pragma unroll
      for (int mfa = 0; mfa < 4; ++mfa) {
        int row = wr * 64 + mfa * 16 + l15;
        ushort4v pk;
#pragma unroll
        for (int i = 0; i < 4; ++i) pk[i] = f2bf(acc[mfa][nfb][i] + bv[i]);
        *(ushort4v*)(Bs + row * ROWB + (colb ^ ((row & 7) << 4))) = pk;
      }
    }
    __syncthreads();
    const int srow = tid >> 2, seg = tid & 3;
#pragma unroll
    for (int rr = 0; rr < 2; ++rr) {
      int row = srow + rr * 64;
      int x = (row & 7) << 4;
      ushort* gdst = (ushort*)outp + (size_t)(row0 + row) * 256 + pcol;
#pragma unroll
      for (int it = 0; it < 4; ++it) {
        int colb = seg * 16 + it * 64;
        uint4 v = *(const uint4*)(Bs + row * ROWB + (colb ^ x));
        *(uint4*)(gdst + colb / 2) = v;
      }
    }
  } else {
    float* red1 = redbuf;
    float* red2 = redbuf + 512;
    float* mv_ = redbuf + 1024;
    float* rv_ = redbuf + 1152;
    float s1[4] = {0.f, 0.f, 0.f, 0.f}, s2[4] = {0.f, 0.f, 0.f, 0.f};
#pragma unroll
    for (int nfb = 0; nfb < 4; ++nfb) {
      int col0 = wc * 64 + nfb * 16 + l4 * 4;
      f32x4 bv = *(const f32x4*)(bias + col0);
#pragma unroll
      for (int mfa = 0; mfa < 4; ++mfa) {
        size_t row = (size_t)row0 + wr * 64 + mfa * 16 + l15;
        ushort4v rz = *(const ushort4v*)(A + row * 256 + col0);
#pragma unroll
        for (int i = 0; i < 4; ++i) {
          float zz = bf2f(rz[i]) + fmaxf(acc[mfa][nfb][i] + bv[i], 0.f);
          acc[mfa][nfb][i] = zz;
          s1[mfa] += zz;
          s2[mfa] += zz * zz;
        }
      }
    }
#pragma unroll
    for (int mfa = 0; mfa < 4; ++mfa) {
      s1[mfa] += __shfl_xor(s1[mfa], 16); s1[mfa] += __shfl_xor(s1[mfa], 32);
      s2[mfa] += __shfl_xor(s2[mfa], 16); s2[mfa] += __shfl_xor(s2[mfa], 32);
    }
    if (l4 == 0) {
#pragma unroll
      for (int mfa = 0; mfa < 4; ++mfa) {
        red1[wc * 128 + wr * 64 + mfa * 16 + l15] = s1[mfa];
        red2[wc * 128 + wr * 64 + mfa * 16 + l15] = s2[mfa];
      }
    }
    __syncthreads();
    if (tid < 128) {
      float m1 = red1[tid] + red1[128 + tid] + red1[256 + tid] + red1[384 + tid];
      float m2 = red2[tid] + red2[128 + tid] + red2[256 + tid] + red2[384 + tid];
      float mean = m1 * 0.00390625f;
      float var = m2 * 0.00390625f - mean * mean;
      mv_[tid] = mean;
      rv_[tid] = rsqrtf(var + 1e-5f);
    }
    __syncthreads();
#pragma unroll
    for (int nfb = 0; nfb < 4; ++nfb) {
      int col0 = wc * 64 + nfb * 16 + l4 * 4;
      f32x4 gg = *(const f32x4*)(lng + col0);
      f32x4 bb = *(const f32x4*)(lnb + col0);
      int colb = col0 * 2;
#pragma unroll
      for (int mfa = 0; mfa < 4; ++mfa) {
        int lr = wr * 64 + mfa * 16 + l15;
        float mean = mv_[lr], rs = rv_[lr];
        if constexpr (OUTF32) {
          f32x4 w;
#pragma unroll
          for (int i = 0; i < 4; ++i) w[i] = (acc[mfa][nfb][i] - mean) * rs * gg[i] + bb[i];
          *(f32x4*)((float*)outp + ((size_t)row0 + lr) * 256 + col0) = w;
        } else {
          ushort4v pk;
#pragma unroll
          for (int i = 0; i < 4; ++i) pk[i] = f2bf((acc[mfa][nfb][i] - mean) * rs * gg[i] + bb[i]);
          *(ushort4v*)(Bs + lr * ROWB + (colb ^ ((lr & 7) << 4))) = pk;
        }
      }
    }
    if constexpr (!OUTF32) {
      __syncthreads();
      const int srow = tid >> 2, seg = tid & 3;
      int x = (srow & 7) << 4;
      ushort* gdst = (ushort*)outp + (size_t)(row0 + srow) * 256;
#pragma unroll
      for (int it = 0; it < 8; ++it) {
        int colb = seg * 16 + it * 64;
        uint4 v = *(const uint4*)(Bs + srow * ROWB + (colb ^ x));
        *(uint4*)(gdst + colb / 2) = v;
      }
    }
  }
}

// ---------------- attn_big: nq small (64/32), nk=2048, masked, q shared across batch ----
template <int MF>
__global__ __launch_bounds__(512) void attn_big(
    const ushort* __restrict__ qb, const ushort* __restrict__ kb,
    const ushort* __restrict__ vb, const float* __restrict__ mask,
    ushort* __restrict__ O)
{
  __shared__ __align__(16) ushort Ps[8][64][72];
  __shared__ __align__(16) ushort Vt[8][32][72];
  const int h = blockIdx.x, b = blockIdx.y;
  const int tid = threadIdx.x;
  const int w = tid >> 6, lane = tid & 63;
  const int l15 = lane & 15, l4 = lane >> 4;
  const int koff = l4 * 8;
  const int kvbase = b * 2048;

  short8 qf[MF];
#pragma unroll
  for (int mf = 0; mf < MF; ++mf)
    qf[mf] = *(const short8*)(qb + (size_t)(mf * 16 + l15) * 256 + h * 32 + koff);

  f32x4 Oa[MF][2];
  float Mr[MF][4], Lr[MF][4];
#pragma unroll
  for (int mf = 0; mf < MF; ++mf) {
    Oa[mf][0] = (f32x4)0.f; Oa[mf][1] = (f32x4)0.f;
#pragma unroll
    for (int r = 0; r < 4; ++r) { Mr[mf][r] = -1e30f; Lr[mf][r] = 0.f; }
  }

  for (int c = 0; c < 4; ++c) {
    const int kc = w * 256 + c * 64;
    f32x4 S[MF][4];
#pragma unroll
    for (int nf = 0; nf < 4; ++nf) {
      short8 kf = *(const short8*)(kb + (size_t)(kvbase + kc + nf * 16 + l15) * 256 + h * 32 + koff);
#pragma unroll
      for (int mf = 0; mf < MF; ++mf)
        S[mf][nf] = __builtin_amdgcn_mfma_f32_16x16x32_bf16(qf[mf], kf, (f32x4)0.f, 0, 0, 0);
    }
    float mv[4];
#pragma unroll
    for (int nf = 0; nf < 4; ++nf)
      mv[nf] = mask[(size_t)b * 2048 + kc + nf * 16 + l15];
#pragma unroll
    for (int mf = 0; mf < MF; ++mf)
#pragma unroll
      for (int nf = 0; nf < 4; ++nf)
#pragma unroll
        for (int r = 0; r < 4; ++r) {
          float s = S[mf][nf][r] * 0.0625f;
          S[mf][nf][r] = (mv[nf] != 0.f) ? s : -1e4f;
        }
#pragma unroll
    for (int mf = 0; mf < MF; ++mf)
#pragma unroll
      for (int r = 0; r < 4; ++r) {
        float pm = fmaxf(fmaxf(S[mf][0][r], S[mf][1][r]), fmaxf(S[mf][2][r], S[mf][3][r]));
        pm = fmaxf(pm, __shfl_xor(pm, 1));
        pm = fmaxf(pm, __shfl_xor(pm, 2));
        pm = fmaxf(pm, __shfl_xor(pm, 4));
        pm = fmaxf(pm, __shfl_xor(pm, 8));
        float Mnew = fmaxf(Mr[mf][r], pm);
        float corr = __expf(Mr[mf][r] - Mnew);
        Mr[mf][r] = Mnew;
        float rs = 0.f;
#pragma unroll
        for (int nf = 0; nf < 4; ++nf) {
          float p = __expf(S[mf][nf][r] - Mnew);
          S[mf][nf][r] = p;
          rs += p;
        }
        rs += __shfl_xor(rs, 1);
        rs += __shfl_xor(rs, 2);
        rs += __shfl_xor(rs, 4);
        rs += __shfl_xor(rs, 8);
        Lr[mf][r] = Lr[mf][r] * corr + rs;
        Oa[mf][0][r] *= corr;
        Oa[mf][1][r] *= corr;
      }
#pragma unroll
    for (int dblk = 0; dblk < 4; ++dblk) {
      short8 vv = *(const short8*)(vb + (size_t)(kvbase + kc + lane) * 256 + h * 32 + dblk * 8);
#pragma unroll
      for (int j = 0; j < 8; ++j) Vt[w][dblk * 8 + j][lane] = (ushort)vv[j];
    }
#pragma unroll
    for (int mf = 0; mf < MF; ++mf)
#pragma unroll
      for (int nf = 0; nf < 4; ++nf)
#pragma unroll
        for (int r = 0; r < 4; ++r)
          Ps[w][mf * 16 + l4 * 4 + r][nf * 16 + l15] = f2bf(S[mf][nf][r]);
#pragma unroll
    for (int ks = 0; ks < 2; ++ks) {
      short8 pf[MF];
#pragma unroll
      for (int mf = 0; mf < MF; ++mf)
        pf[mf] = *(const short8*)&Ps[w][mf * 16 + l15][ks * 32 + koff];
#pragma unroll
      for (int nf2 = 0; nf2 < 2; ++nf2) {
        short8 vf = *(const short8*)&Vt[w][nf2 * 16 + l15][ks * 32 + koff];
#pragma unroll
        for (int mf = 0; mf < MF; ++mf)
          Oa[mf][nf2] = __builtin_amdgcn_mfma_f32_16x16x32_bf16(pf[mf], vf, Oa[mf][nf2], 0, 0, 0);
      }
    }
  }

  __syncthreads();
  float* Mw = (float*)&Ps[0][0][0];
  float* Lw = Mw + 512;
  float* Ow = Lw + 512;  // [8][64][33]
#pragma unroll
  for (int mf = 0; mf < MF; ++mf)
#pragma unroll
    for (int r = 0; r < 4; ++r) {
      int row = mf * 16 + l4 * 4 + r;
      if (l15 == 0) { Mw[w * 64 + row] = Mr[mf][r]; Lw[w * 64 + row] = Lr[mf][r]; }
#pragma unroll
      for (int nf2 = 0; nf2 < 2; ++nf2)
        Ow[(w * 64 + row) * 33 + nf2 * 16 + l15] = Oa[mf][nf2][r];
    }
  __syncthreads();
  const int NQ = MF * 16;
  int row = tid >> 3, dg = tid & 7;
  if (row < NQ) {
    float mm = -1e30f;
#pragma unroll
    for (int s = 0; s < 8; ++s) mm = fmaxf(mm, Mw[s * 64 + row]);
    float den = 0.f, es[8];
#pragma unroll
    for (int s = 0; s < 8; ++s) {
      es[s] = __expf(Mw[s * 64 + row] - mm);
      den += Lw[s * 64 + row] * es[s];
    }
    float invden = 1.f / den;
    ushort4v pk;
#pragma unroll
    for (int i = 0; i < 4; ++i) {
      int d = dg * 4 + i;
      float num = 0.f;
#pragma unroll
      for (int s = 0; s < 8; ++s) num += Ow[(s * 64 + row) * 33 + d] * es[s];
      float qv = bf2f(qb[(size_t)row * 256 + h * 32 + d]);
      pk[i] = f2bf(qv + num * invden);
    }
    *(ushort4v*)(O + (size_t)(b * NQ + row) * 256 + h * 32 + dg * 4) = pk;
  }
}

// ---------------- mab1_fused: q-proj + attention(nk=64) + LN0 + Wo + LN1 ----------------
// grid(qt=32, b=32), block 512 = 8 waves = 8 heads over the same 64 q-rows.
// LDS ~74.5KB -> 2 blocks/CU. P staged per-mf per-K-half; V^T in two 32-key halves
// (half B preloaded to regs, written after half-A MFMAs). o_s overlays Qs.
__global__ __launch_bounds__(512, 4) void mab1_fused(
    const ushort* __restrict__ xb, const ushort* __restrict__ wq,
    const float* __restrict__ bq,
    const ushort* __restrict__ kb, const ushort* __restrict__ vb,
    const ushort* __restrict__ wo, const float* __restrict__ bo,
    const float* __restrict__ g0, const float* __restrict__ b0v,
    const float* __restrict__ g1, const float* __restrict__ b1v,
    ushort* __restrict__ outb)
{
  __shared__ __align__(16) ushort Qs[8][64][40];   // 40KB q tiles; later o_s[64][264]
  __shared__ __align__(16) ushort Psh[8][16][40];  // 10KB P half-tile (per-mf staging)
  __shared__ __align__(16) ushort Vth[8][32][40];  // 20KB V^T half (32 keys)
  __shared__ float red1[8][64], red2[8][64], mv_[64], rv_[64];
  ushort* o_s = &Qs[0][0][0];
  constexpr int OS = 264;  // 33792B <= 40960B (Qs)

  const int qt = blockIdx.x, b = blockIdx.y;
  const int tid = threadIdx.x;
  const int w = tid >> 6, lane = tid & 63;  // w = head / col-group
  const int l15 = lane & 15, l4 = lane >> 4;
  const int koff = l4 * 8;
  const size_t row0 = (size_t)b * 2048 + qt * 64;
  const int kvbase = b * 64;
  const int h = w;

  // ---- phase 0: K frags; V half A -> Vth; V half B -> regs ----
  short8 kf[4];
#pragma unroll
  for (int nf = 0; nf < 4; ++nf)
    kf[nf] = *(const short8*)(kb + (size_t)(kvbase + nf * 16 + l15) * 256 + h * 32 + koff);
  const int key = lane & 31, dh2 = lane >> 5;  // key within half; d 16-half
  short8 vvB0, vvB1;
  {
    const ushort* vsrcA = vb + (size_t)(kvbase + key) * 256 + h * 32 + dh2 * 16;
    const ushort* vsrcB = vb + (size_t)(kvbase + 32 + key) * 256 + h * 32 + dh2 * 16;
    short8 vvA0 = *(const short8*)vsrcA;
    short8 vvA1 = *(const short8*)(vsrcA + 8);
    vvB0 = *(const short8*)vsrcB;
    vvB1 = *(const short8*)(vsrcB + 8);
#pragma unroll
    for (int j = 0; j < 8; ++j) Vth[w][dh2 * 16 + j][key] = (ushort)vvA0[j];
#pragma unroll
    for (int j = 0; j < 8; ++j) Vth[w][dh2 * 16 + 8 + j][key] = (ushort)vvA1[j];
  }

  // ---- phase 1: q[64][32] (head w) = xb[rows] @ Wq[:, w*32..] + bq -> Qs (bf16) ----
  {
    f32x4 qa[4][2];
#pragma unroll
    for (int i = 0; i < 4; ++i) { qa[i][0] = (f32x4)0.f; qa[i][1] = (f32x4)0.f; }
#pragma unroll
    for (int ks = 0; ks < 8; ++ks) {
      short8 af[4];
#pragma unroll
      for (int mfa = 0; mfa < 4; ++mfa)
        af[mfa] = *(const short8*)(xb + (row0 + mfa * 16 + l15) * 256 + ks * 32 + koff);
#pragma unroll
      for (int nfb = 0; nfb < 2; ++nfb) {
        int n = w * 32 + nfb * 16 + l15;
        short8 bf = *(const short8*)(wq + (size_t)n * 256 + ks * 32 + koff);
#pragma unroll
        for (int mfa = 0; mfa < 4; ++mfa)  // swapped: D row<-l15(A row), col<-l4*4+i (n)
          qa[mfa][nfb] = __builtin_amdgcn_mfma_f32_16x16x32_bf16(bf, af[mfa], qa[mfa][nfb], 0, 0, 0);
      }
    }
#pragma unroll
    for (int nfb = 0; nfb < 2; ++nfb) {
      f32x4 bv = *(const f32x4*)(bq + w * 32 + nfb * 16 + l4 * 4);
#pragma unroll
      for (int mfa = 0; mfa < 4; ++mfa) {
        ushort4v pk;
#pragma unroll
        for (int i = 0; i < 4; ++i) pk[i] = f2bf(qa[mfa][nfb][i] + bv[i]);
        *(ushort4v*)&Qs[w][mfa * 16 + l15][nfb * 16 + l4 * 4] = pk;
      }
    }
  }

  // ---- phase 2: QK^T + softmax ----
  short8 qf[4];
#pragma unroll
  for (int mf = 0; mf < 4; ++mf)
    qf[mf] = *(const short8*)&Qs[w][mf * 16 + l15][koff];

  f32x4 S[4][4];
#pragma unroll
  for (int nf = 0; nf < 4; ++nf) {
#pragma unroll
    for (int mf = 0; mf < 4; ++mf)
      S[mf][nf] = __builtin_amdgcn_mfma_f32_16x16x32_bf16(qf[mf], kf[nf], (f32x4)0.f, 0, 0, 0);
  }
  float Lr[4][4];
#pragma unroll
  for (int mf = 0; mf < 4; ++mf)
#pragma unroll
    for (int r = 0; r < 4; ++r) {
      float pm = fmaxf(fmaxf(S[mf][0][r], S[mf][1][r]), fmaxf(S[mf][2][r], S[mf][3][r])) * 0.0625f;
      pm = fmaxf(pm, __shfl_xor(pm, 1));
      pm = fmaxf(pm, __shfl_xor(pm, 2));
      pm = fmaxf(pm, __shfl_xor(pm, 4));
      pm = fmaxf(pm, __shfl_xor(pm, 8));
      float rs = 0.f;
#pragma unroll
      for (int nf = 0; nf < 4; ++nf) {
        float p = __expf(S[mf][nf][r] * 0.0625f - pm);
        S[mf][nf][r] = p;
        rs += p;
      }
      rs += __shfl_xor(rs, 1);
      rs += __shfl_xor(rs, 2);
      rs += __shfl_xor(rs, 4);
      rs += __shfl_xor(rs, 8);
      Lr[mf][r] = rs;
    }

  // ---- PV: half A (keys 0-31), per-mf P staging; then half B ----
  f32x4 Oa[4][2];
#pragma unroll
  for (int mf = 0; mf < 4; ++mf) { Oa[mf][0] = (f32x4)0.f; Oa[mf][1] = (f32x4)0.f; }
#pragma unroll
  for (int mf = 0; mf < 4; ++mf) {
#pragma unroll
    for (int nf = 0; nf < 2; ++nf)
#pragma unroll
      for (int r = 0; r < 4; ++r)
        Psh[w][l4 * 4 + r][nf * 16 + l15] = f2bf(S[mf][nf][r]);
    short8 pf = *(const short8*)&Psh[w][l15][koff];
#pragma unroll
    for (int nf2 = 0; nf2 < 2; ++nf2) {
      short8 vf = *(const short8*)&Vth[w][nf2 * 16 + l15][koff];
      Oa[mf][nf2] = __builtin_amdgcn_mfma_f32_16x16x32_bf16(pf, vf, Oa[mf][nf2], 0, 0, 0);
    }
  }
  // swap Vth to half B (wave-private; LDS ops in-order per wave)
#pragma unroll
  for (int j = 0; j < 8; ++j) Vth[w][dh2 * 16 + j][key] = (ushort)vvB0[j];
#pragma unroll
  for (int j = 0; j < 8; ++j) Vth[w][dh2 * 16 + 8 + j][key] = (ushort)vvB1[j];
#pragma unroll
  for (int mf = 0; mf < 4; ++mf) {
#pragma unroll
    for (int nf = 0; nf < 2; ++nf)
#pragma unroll
      for (int r = 0; r < 4; ++r)
        Psh[w][l4 * 4 + r][nf * 16 + l15] = f2bf(S[mf][nf + 2][r]);
    short8 pf = *(const short8*)&Psh[w][l15][koff];
#pragma unroll
    for (int nf2 = 0; nf2 < 2; ++nf2) {
      short8 vf = *(const short8*)&Vth[w][nf2 * 16 + l15][koff];
      Oa[mf][nf2] = __builtin_amdgcn_mfma_f32_16x16x32_bf16(pf, vf, Oa[mf][nf2], 0, 0, 0);
    }
  }

  // ---- phase 3: o = q + PV/L; LN0 stats ----
  {
    float s1[4][4], s2[4][4];
#pragma unroll
    for (int mf = 0; mf < 4; ++mf)
#pragma unroll
      for (int r = 0; r < 4; ++r) {
        float invL = 1.f / Lr[mf][r];
        s1[mf][r] = 0.f; s2[mf][r] = 0.f;
#pragma unroll
        for (int nf2 = 0; nf2 < 2; ++nf2) {
          float qv = bf2f(Qs[w][mf * 16 + l4 * 4 + r][nf2 * 16 + l15]);
          float z = qv + Oa[mf][nf2][r] * invL;
          Oa[mf][nf2][r] = z;
          s1[mf][r] += z;
          s2[mf][r] += z * z;
        }
#pragma unroll
        for (int off = 1; off < 16; off <<= 1) {
          s1[mf][r] += __shfl_xor(s1[mf][r], off);
          s2[mf][r] += __shfl_xor(s2[mf][r], off);
        }
        if (l15 == 0) {
          int row = mf * 16 + l4 * 4 + r;
          red1[w][row] = s1[mf][r];
          red2[w][row] = s2[mf][r];
        }
      }
  }
  __syncthreads();  // all Qs reads done (o_s overlays Qs); red complete
  if (tid < 64) {
    float m1 = 0.f, m2 = 0.f;
#pragma unroll
    for (int s = 0; s < 8; ++s) { m1 += red1[s][tid]; m2 += red2[s][tid]; }
    float mean = m1 * 0.00390625f;
    float var = m2 * 0.00390625f - mean * mean;
    mv_[tid] = mean;
    rv_[tid] = rsqrtf(var + 1e-5f);
  }
  __syncthreads();
  // apply LN0 -> o_s (overlay on Qs)
#pragma unroll
  for (int nf2 = 0; nf2 < 2; ++nf2) {
    int col = h * 32 + nf2 * 16 + l15;
    float gc = g0[col], bc = b0v[col];
#pragma unroll
    for (int mf = 0; mf < 4; ++mf)
#pragma unroll
      for (int r = 0; r < 4; ++r) {
        int row = mf * 16 + l4 * 4 + r;
        float v = (Oa[mf][nf2][r] - mv_[row]) * rv_[row] * gc + bc;
        o_s[row * OS + col] = f2bf(v);
      }
  }
  __syncthreads();

  // ---- phase 4: Wo GEMM (cols w*32..) + resid + LN1 ----
  f32x4 oa[4][2];
#pragma unroll
  for (int i = 0; i < 4; ++i) { oa[i][0] = (f32x4)0.f; oa[i][1] = (f32x4)0.f; }
#pragma unroll
  for (int ks = 0; ks < 8; ++ks) {
    short8 af[4];
#pragma unroll
    for (int mfa = 0; mfa < 4; ++mfa)
      af[mfa] = *(const short8*)&o_s[(mfa * 16 + l15) * OS + ks * 32 + koff];
#pragma unroll
    for (int nfb = 0; nfb < 2; ++nfb) {
      int n = w * 32 + nfb * 16 + l15;
      short8 bf = *(const short8*)(wo + (size_t)n * 256 + ks * 32 + koff);
#pragma unroll
      for (int mfa = 0; mfa < 4; ++mfa)
        oa[mfa][nfb] = __builtin_amdgcn_mfma_f32_16x16x32_bf16(bf, af[mfa], oa[mfa][nfb], 0, 0, 0);
    }
  }
  float t1[4] = {0.f, 0.f, 0.f, 0.f}, t2[4] = {0.f, 0.f, 0.f, 0.f};
#pragma unroll
  for (int nfb = 0; nfb < 2; ++nfb) {
    int col0 = w * 32 + nfb * 16 + l4 * 4;
    f32x4 bv = *(const f32x4*)(bo + col0);
#pragma unroll
    for (int mfa = 0; mfa < 4; ++mfa) {
      int row = mfa * 16 + l15;
      ushort4v rz = *(const ushort4v*)&o_s[row * OS + col0];
#pragma unroll
      for (int i = 0; i < 4; ++i) {
        float zz = bf2f(rz[i]) + fmaxf(oa[mfa][nfb][i] + bv[i], 0.f);
        oa[mfa][nfb][i] = zz;
        t1[mfa] += zz;
        t2[mfa] += zz * zz;
      }
    }
  }
#pragma unroll
  for (int mfa = 0; mfa < 4; ++mfa) {
    t1[mfa] += __shfl_xor(t1[mfa], 16); t1[mfa] += __shfl_xor(t1[mfa], 32);
    t2[mfa] += __shfl_xor(t2[mfa], 16); t2[mfa] += __shfl_xor(t2[mfa], 32);
  }
  if (l4 == 0) {
#pragma unroll
    for (int mfa = 0; mfa < 4; ++mfa) {
      red1[w][mfa * 16 + l15] = t1[mfa];
      red2[w][mfa * 16 + l15] = t2[mfa];
    }
  }
  __syncthreads();
  if (tid < 64) {
    float m1 = 0.f, m2 = 0.f;
#pragma unroll
    for (int s = 0; s < 8; ++s) { m1 += red1[s][tid]; m2 += red2[s][tid]; }
    float mean = m1 * 0.00390625f;
    float var = m2 * 0.00390625f - mean * mean;
    mv_[tid] = mean;
    rv_[tid] = rsqrtf(var + 1e-5f);
  }
  __syncthreads();
#pragma unroll
  for (int nfb = 0; nfb < 2; ++nfb) {
    int col0 = w * 32 + nfb * 16 + l4 * 4;
    f32x4 gg = *(const f32x4*)(g1 + col0);
    f32x4 bb = *(const f32x4*)(b1v + col0);
#pragma unroll
    for (int mfa = 0; mfa < 4; ++mfa) {
      int row = mfa * 16 + l15;
      ushort4v pk;
#pragma unroll
      for (int i = 0; i < 4; ++i)
        pk[i] = f2bf((oa[mfa][nfb][i] - mv_[row]) * rv_[row] * gg[i] + bb[i]);
      *(ushort4v*)&o_s[row * OS + col0] = pk;  // per-lane same addr as resid read: safe
    }
  }
  __syncthreads();
  // cooperative full-line store: 512 thr -> 64 rows x 8 segs of 64B
  {
    const int r_ = tid >> 3, sg = tid & 7;
    ushort* gdst = outb + (row0 + r_) * 256 + sg * 32;
    const ushort* src = &o_s[r_ * OS + sg * 32];
#pragma unroll
    for (int it = 0; it < 4; ++it) {
      uint4 v = *(const uint4*)(src + it * 8);
      *(uint4*)(gdst + it * 8) = v;
    }
  }
}

// ---------------- small LayerNorm: bf16 in/out, wave per row ----------------
__global__ __launch_bounds__(256) void ln4(
    const ushort* __restrict__ in, ushort* __restrict__ out,
    const float* __restrict__ g, const float* __restrict__ bb)
{
  const int w = threadIdx.x >> 6, lane = threadIdx.x & 63;
  const size_t row = (size_t)blockIdx.x * 4 + w;
  ushort4v u = *(const ushort4v*)(in + row * 256 + lane * 4);
  float v[4];
#pragma unroll
  for (int i = 0; i < 4; ++i) v[i] = bf2f(u[i]);
  float s1 = v[0] + v[1] + v[2] + v[3];
  float s2 = v[0] * v[0] + v[1] * v[1] + v[2] * v[2] + v[3] * v[3];
#pragma unroll
  for (int off = 1; off < 64; off <<= 1) {
    s1 += __shfl_xor(s1, off);
    s2 += __shfl_xor(s2, off);
  }
  float mean = s1 * 0.00390625f;
  float var = s2 * 0.00390625f - mean * mean;
  float rs = rsqrtf(var + 1e-5f);
  f32x4 gg = *(const f32x4*)(g + lane * 4);
  f32x4 bv = *(const f32x4*)(bb + lane * 4);
  ushort4v p;
#pragma unroll
  for (int i = 0; i < 4; ++i) p[i] = f2bf((v[i] - mean) * rs * gg[i] + bv[i]);
  *(ushort4v*)(out + row * 256 + lane * 4) = p;
}

extern "C" void kernel_launch(void* const* d_in, const int* in_sizes, int n_in,
                              void* d_out, int out_size, void* d_ws, size_t ws_size,
                              hipStream_t stream) {
  const float* xv = (const float*)d_in[0];
  const float* yt = (const float*)d_in[1];
  const float* pmask = (const float*)d_in[2];
  const float* prW = (const float*)d_in[3];
  const float* prb = (const float*)d_in[4];
  const float* iI = (const float*)d_in[5];
  const float* iWq = (const float*)d_in[6];
  const float* ibq = (const float*)d_in[7];
  const float* iWk = (const float*)d_in[8];
  const float* ibk = (const float*)d_in[9];
  const float* iWv = (const float*)d_in[10];
  const float* ibv = (const float*)d_in[11];
  const float* iWo = (const float*)d_in[12];
  const float* ibo = (const float*)d_in[13];
  const float* ig0 = (const float*)d_in[14];
  const float* ib0 = (const float*)d_in[15];
  const float* ig1 = (const float*)d_in[16];
  const float* ib1 = (const float*)d_in[17];
  const float* pS = (const float*)d_in[18];
  const float* pWq = (const float*)d_in[19];
  const float* pbq = (const float*)d_in[20];
  const float* pWk = (const float*)d_in[21];
  const float* pbk = (const float*)d_in[22];
  const float* pWv = (const float*)d_in[23];
  const float* pbv = (const float*)d_in[24];
  const float* pWo = (const float*)d_in[25];
  const float* pbo = (const float*)d_in[26];
  const float* pg0 = (const float*)d_in[27];
  const float* pb0 = (const float*)d_in[28];
  const float* pg1 = (const float*)d_in[29];
  const float* pb1 = (const float*)d_in[30];

  char* ws = (char*)d_ws;
  if (ws_size < 172621824u) return;
  ushort* xb = (ushort*)(ws + 0);              // 32MB (B*N x 256)
  ushort* ob = (ushort*)(ws + 33554432);       // 32MB (attn/LN scratch)
  ushort* hb = (ushort*)(ws + 67108864);       // 1MB  (B*NI x 256)
  ushort* kbw = (ushort*)(ws + 101711872);     // 32MB
  ushort* vbw = (ushort*)(ws + 135266304);     // 32MB
  ushort* wt = (ushort*)(ws + 168820736);      // 3.5MB transposed weights
  ushort* q_all = (ushort*)(ws + 172490752);   // 112KB tiny-q outputs

  prep_weights<<<dim3(16, 28), 256, 0, stream>>>(iWq, iWk, iWv, iWo, pWq, pWk, pWv, pWo, wt);
  proj_gelu<<<8192, 256, 0, stream>>>(xv, yt, prW, prb, xb);
  gemm_q<<<4, 256, 0, stream>>>(iI, pS, wt, ibq, pbq, q_all);

  for (int l = 0; l < 3; ++l) {
    const int s0 = l * 2, s1 = l * 2 + 1;
    const ushort* wk = wt + (size_t)(l * 8 + 1) * 65536;
    const ushort* wv = wt + (size_t)(l * 8 + 2) * 65536;
    const ushort* wo0 = wt + (size_t)(l * 8 + 3) * 65536;
    const ushort* wq1 = wt + (size_t)(l * 8 + 4) * 65536;
    const ushort* wk1 = wt + (size_t)(l * 8 + 5) * 65536;
    const ushort* wv1 = wt + (size_t)(l * 8 + 6) * 65536;
    const ushort* wo1 = wt + (size_t)(l * 8 + 7) * 65536;
    // ---- mab0 K,V (consume xb): batched, A-sharers colocated on one XCD ----
    gemm_bp<0, false, 128><<<2048, 256, 0, stream>>>(
        xb, wk, wv, wv, ibk + s0 * 256, ibv + s0 * 256, ibv + s0 * 256,
        kbw, vbw, vbw, nullptr, nullptr, 2, 4);
    attn_big<4><<<dim3(8, 32), 512, 0, stream>>>(q_all + l * 16384, kbw, vbw, pmask, ob);
    ln4<<<512, 256, 0, stream>>>(ob, ob, ig0 + s0 * 256, ib0 + s0 * 256);
    gemm_bp<3, false, 256><<<16, 512, 0, stream>>>(
        ob, wo0, wo0, wo0, ibo + s0 * 256, ibo + s0 * 256, ibo + s0 * 256,
        hb, hb, hb, ig1 + s0 * 256, ib1 + s0 * 256, 1, 1);
    // ---- mab1 K,V (consume hb) ----
    gemm_bp<0, false, 128><<<64, 256, 0, stream>>>(
        hb, wk1, wv1, wv1, ibk + s1 * 256, ibv + s1 * 256, ibv + s1 * 256,
        kbw, vbw, vbw, nullptr, nullptr, 2, 4);
    // ---- mab1 fused: q-proj + attention + LN0 + Wo + LN1, xb in-place ----
    mab1_fused<<<dim3(32, 32), 512, 0, stream>>>(
        xb, wq1, ibq + s1 * 256, kbw, vbw, wo1, ibo + s1 * 256,
        ig0 + s1 * 256, ib0 + s1 * 256, ig1 + s1 * 256, ib1 + s1 * 256, xb);
  }
  // ---- PMA: S attends to x ----
  gemm_bp<0, false, 128><<<2048, 256, 0, stream>>>(
      xb, wt + (size_t)25 * 65536, wt + (size_t)26 * 65536, wt + (size_t)26 * 65536,
      pbk, pbv, pbv, kbw, vbw, vbw, nullptr, nullptr, 2, 4);
  attn_big<2><<<dim3(8, 32), 512, 0, stream>>>(q_all + 49152, kbw, vbw, pmask, ob);
  ln4<<<256, 256, 0, stream>>>(ob, ob, pg0, pb0);
  gemm_bp<3, true, 256><<<8, 512, 0, stream>>>(
      ob, wt + (size_t)27 * 65536, wt + (size_t)27 * 65536, wt + (size_t)27 * 65536,
      pbo, pbo, pbo, d_out, d_out, d_out, pg1, pb1, 1, 1);
}